// Round 8
// baseline (314.024 us; speedup 1.0000x reference)
//
#include <hip/hip_runtime.h>
#include <math.h>

#define BB 1024
#define TT 50
#define FF 48
#define EXTN 60
#define NFREQ 31

typedef _Float16 h8 __attribute__((ext_vector_type(8)));
typedef _Float16 h4 __attribute__((ext_vector_type(4)));
typedef float f4 __attribute__((ext_vector_type(4)));

__device__ __forceinline__ float fast_tanh(float x) {
    float e = __expf(2.0f * x);
    return 1.0f - 2.0f * __builtin_amdgcn_rcpf(e + 1.0f);
}

// =============== prep: pack ALL weights into MFMA-fragment order ===============
// Main P layout (per layer): tile t8 = (wv*16+ks)*8+nt ; P[t8*512 + lane*8 + j] =
//   W[k = ks*32+(lane>>4)*8+j][n = wv*128+nt*16+(lane&15)]  -> frag load = base+lane*16.
__global__ void prep_kernel(const float* __restrict__ gcb_w, _Float16* __restrict__ P,
                            const float* __restrict__ gc1_w, _Float16* __restrict__ P1,
                            const float* __restrict__ gc7_w, _Float16* __restrict__ P7,
                            const float* __restrict__ mlp_w1, _Float16* __restrict__ Pw1,
                            const float* __restrict__ mlp_w2, _Float16* __restrict__ Pw2,
                            const float* __restrict__ gc1_att, const float* __restrict__ gcb_att,
                            const float* __restrict__ gc7_att, _Float16* __restrict__ attp,
                            float* __restrict__ dctm, float* __restrict__ dtail) {
    int blk = blockIdx.x, tid = threadIdx.x;
    const _Float16 HZ = (_Float16)0.0f;
    if (blk < 512) {                    // big-layer weights, 4 x 512KB
        int z = blk >> 7;
        int idx = ((blk & 127) << 8) | tid;
        int lane = idx & 63, t8 = idx >> 6;
        int nt = t8 & 7, kw = t8 >> 3;
        int ks = kw & 15, wv = kw >> 4;
        int n = wv * 128 + nt * 16 + (lane & 15);
        int k0 = ks * 32 + (lane >> 4) * 8;
        const float* src = gcb_w + (size_t)z * 262144 + n;
        h8 v;
        #pragma unroll
        for (int j = 0; j < 8; ++j) v[j] = (_Float16)src[(size_t)(k0 + j) * 512];
        *(h8*)(P + (size_t)z * 262144 + (size_t)idx * 8) = v;
    } else if (blk < 528) {             // L1 weights (K=64 padded)
        int idx = ((blk - 512) << 8) | tid;
        int lane = idx & 63, t8 = idx >> 6;
        int nt = t8 & 7, kw = t8 >> 3;
        int ks = kw & 1, wv = kw >> 1;
        int n = wv * 128 + nt * 16 + (lane & 15);
        int k0 = ks * 32 + (lane >> 4) * 8;
        h8 v;
        #pragma unroll
        for (int j = 0; j < 8; ++j) v[j] = (k0 + j < 10) ? (_Float16)gc1_w[(k0 + j) * 512 + n] : HZ;
        *(h8*)(P1 + (size_t)idx * 8) = v;
    } else if (blk < 532) {             // L6 weights (N=16 padded, k split across waves)
        int idx = ((blk - 528) << 8) | tid;
        int lane = idx & 63, t8 = idx >> 6;     // 0..15
        int ks = t8 & 3, wv = t8 >> 2;
        int n = lane & 15;
        int k0 = wv * 128 + ks * 32 + (lane >> 4) * 8;
        h8 v;
        #pragma unroll
        for (int j = 0; j < 8; ++j) v[j] = (n < 10) ? (_Float16)gc7_w[(k0 + j) * 10 + n] : HZ;
        *(h8*)(P7 + (size_t)idx * 8) = v;
    } else if (blk < 540) {             // mlp w1 as B-frags (K=64 padded)
        int idx = ((blk - 532) << 8) | tid;     // 0..2047
        int lane = idx & 63, t8 = idx >> 6;     // 0..31 = ((wv*4+nt)*2+ks)
        int ks = t8 & 1, q = t8 >> 1;
        int nt = q & 3, wv = q >> 2;
        int o = wv * 64 + nt * 16 + (lane & 15);
        int k0 = ks * 32 + (lane >> 4) * 8;
        h8 v;
        #pragma unroll
        for (int j = 0; j < 8; ++j) v[j] = (k0 + j < 40) ? (_Float16)mlp_w1[o * 40 + k0 + j] : HZ;
        *(h8*)(Pw1 + (size_t)idx * 8) = v;
    } else if (blk < 542) {             // mlp w2 as A-frags (M=16 padded rows t)
        int idx = ((blk - 540) << 8) | tid;     // 0..511
        int lane = idx & 63, ks = idx >> 6;     // 0..7
        int m = lane & 15;
        int k0 = ks * 32 + (lane >> 4) * 8;
        h8 v;
        #pragma unroll
        for (int j = 0; j < 8; ++j) v[j] = (m < 10) ? (_Float16)mlp_w2[m * 256 + k0 + j] : HZ;
        *(h8*)(Pw2 + (size_t)idx * 8) = v;
    } else if (blk < 614) {             // att matrices, k zero-padded to 64
        int idx = (blk - 542) * 256 + tid;
        if (idx < 18432) {
            int l = idx / 3072, r = (idx % 3072) / 64, m = idx & 63;
            float v = 0.f;
            if (m < 48) {
                v = (l == 0) ? gc1_att[r * 48 + m]
                  : (l <= 4) ? gcb_att[(l - 1) * 2304 + r * 48 + m]
                             : gc7_att[r * 48 + m];
            }
            attp[idx] = (_Float16)v;
        }
    } else {                            // DCT tables
        int idx = (blk - 614) * 256 + tid;
        if (idx < 900) {
            int d = idx / 30, k = idx % 30;
            double w = (d == 0) ? sqrt(1.0 / 30.0) : sqrt(2.0 / 30.0);
            dctm[idx] = (float)(w * cos(M_PI * (k + 0.5) * d / 30.0));
        } else if (idx < 910) {
            int d = idx - 900;
            double w = (d == 0) ? sqrt(1.0 / 30.0) : sqrt(2.0 / 30.0);
            double s = 0.0;
            for (int k = 10; k < 30; ++k) s += w * cos(M_PI * (k + 0.5) * d / 30.0);
            dtail[d] = (float)s;
        }
    }
}

// =============== one GCN layer on LDS-resident state, packed weights ===============
// State S: 48 rows x 1024 B (512 f16), 16B granules XOR-swizzled by (row&7).
// K-loop is register double-buffered: ks+1's weight/A frags load while ks' MFMAs run.
// MODE 0: tanh. MODE 1: tanh + save old state into sv. MODE 2: tanh + add sv.
template<int KSTEPS, int MODE>
__device__ __forceinline__ void gcn_layer(char* S, char* T,
        const _Float16* __restrict__ Pw, const _Float16* __restrict__ attp,
        const float* __restrict__ bias, h4* sv,
        int lane, int wv, int l16, int quad) {
    h8 ab[3][2];
    #pragma unroll
    for (int it = 0; it < 3; ++it)
        #pragma unroll
        for (int ks = 0; ks < 2; ++ks)
            ab[it][ks] = *(const h8*)(attp + (it * 16 + l16) * 64 + ks * 32 + quad * 8);

    f4 acc[3][8];
    #pragma unroll
    for (int mt = 0; mt < 3; ++mt)
        #pragma unroll
        for (int nt = 0; nt < 8; ++nt) acc[mt][nt] = (f4)0.0f;

    const _Float16* Pb = Pw + (size_t)wv * (KSTEPS * 8 * 512) + lane * 8;
    const int xm = l16 & 7;

    h8 b0[8], b1[8], a0[3], a1[3];
    #pragma unroll
    for (int nt = 0; nt < 8; ++nt) b0[nt] = *(const h8*)(Pb + nt * 512);
    __syncthreads();   // state ready
    #pragma unroll
    for (int mt = 0; mt < 3; ++mt)
        a0[mt] = *(h8*)(S + (mt * 16 + l16) * 1024 + ((quad ^ xm) << 4));

    for (int ks2 = 0; ks2 < KSTEPS / 2; ++ks2) {
        const int ksB = 2 * ks2 + 1;
        // prefetch odd step
        #pragma unroll
        for (int nt = 0; nt < 8; ++nt) b1[nt] = *(const h8*)(Pb + (ksB * 8 + nt) * 512);
        #pragma unroll
        for (int mt = 0; mt < 3; ++mt)
            a1[mt] = *(h8*)(S + (mt * 16 + l16) * 1024 + (((ksB * 4 + quad) ^ xm) << 4));
        // compute even step
        #pragma unroll
        for (int mt = 0; mt < 3; ++mt)
            #pragma unroll
            for (int nt = 0; nt < 8; ++nt)
                acc[mt][nt] = __builtin_amdgcn_mfma_f32_16x16x32_f16(a0[mt], b0[nt], acc[mt][nt], 0, 0, 0);
        // prefetch next even step
        if (ks2 + 1 < KSTEPS / 2) {
            const int ksC = 2 * ks2 + 2;
            #pragma unroll
            for (int nt = 0; nt < 8; ++nt) b0[nt] = *(const h8*)(Pb + (ksC * 8 + nt) * 512);
            #pragma unroll
            for (int mt = 0; mt < 3; ++mt)
                a0[mt] = *(h8*)(S + (mt * 16 + l16) * 1024 + (((ksC * 4 + quad) ^ xm) << 4));
        }
        // compute odd step
        #pragma unroll
        for (int mt = 0; mt < 3; ++mt)
            #pragma unroll
            for (int nt = 0; nt < 8; ++nt)
                acc[mt][nt] = __builtin_amdgcn_mfma_f32_16x16x32_f16(a1[mt], b1[nt], acc[mt][nt], 0, 0, 0);
    }
    __syncthreads();   // all reads done; epilogue may overwrite state

    if (lane < 48) {
        int row = lane / 3, s = lane % 3;
        *(h8*)(T + row * 144 + 96 + s * 16) = (h8)(_Float16)0.0f;
    }

    #pragma unroll
    for (int nt = 0; nt < 8; ++nt) {
        #pragma unroll
        for (int mt = 0; mt < 3; ++mt) {
            h4 hv;
            #pragma unroll
            for (int j = 0; j < 4; ++j) hv[j] = (_Float16)acc[mt][nt][j];
            *(h4*)(T + l16 * 144 + (mt * 16 + quad * 4) * 2) = hv;
        }
        asm volatile("s_waitcnt lgkmcnt(0)" ::: "memory");
        h8 tf0 = *(h8*)(T + l16 * 144 + quad * 16);
        h8 tf1 = *(h8*)(T + l16 * 144 + 64 + quad * 16);
        f4 acc2[3];
        #pragma unroll
        for (int it = 0; it < 3; ++it) {
            acc2[it] = __builtin_amdgcn_mfma_f32_16x16x32_f16(tf0, ab[it][0], (f4)0.0f, 0, 0, 0);
            acc2[it] = __builtin_amdgcn_mfma_f32_16x16x32_f16(tf1, ab[it][1], acc2[it], 0, 0, 0);
        }
        const int c0 = wv * 128 + nt * 16 + quad * 4;
        const f4 bv = *(const f4*)(bias + c0);
        #pragma unroll
        for (int it = 0; it < 3; ++it) {
            int f = it * 16 + l16;
            char* sp = S + f * 1024 + (((c0 >> 3) ^ (f & 7)) << 4) + ((c0 & 7) << 1);
            if (MODE == 1) sv[nt * 3 + it] = *(h4*)sp;
            h4 o;
            #pragma unroll
            for (int j = 0; j < 4; ++j) {
                float v = fast_tanh(acc2[it][j] + bv[j]);
                if (MODE == 2) v += (float)sv[nt * 3 + it][j];
                o[j] = (_Float16)v;
            }
            *(h4*)sp = o;
        }
    }
}

// =============== fused GCN: dct_in + L1..L6 + recon, one WG per batch ===============
__launch_bounds__(256, 2)
__global__ void gcn_fused_kernel(const float* __restrict__ seq,
                                 const _Float16* __restrict__ P1,
                                 const _Float16* __restrict__ Pm,
                                 const _Float16* __restrict__ P7,
                                 const _Float16* __restrict__ attp,
                                 const float* __restrict__ gc1_b,
                                 const float* __restrict__ gcb_b,
                                 const float* __restrict__ gc7_b,
                                 const float* __restrict__ dctm,
                                 const float* __restrict__ dtail,
                                 float* __restrict__ fusedb) {
    __shared__ __align__(16) char smem[63744];
    char* S    = smem;              // 48 x 1024 state
    char* R    = smem + 49152;      // 12288: staging / transit / L6 partials / G
    char* dctf = smem + 61440;      // 48 x 12 f32 (dct_in, resid for L6)
    const int tid = threadIdx.x, lane = tid & 63, wv = tid >> 6;
    const int l16 = lane & 15, quad = lane >> 4;
    const int b = blockIdx.x;
    char* T = R + wv * 2304;

    // ---- prologue: seq rows 40..49 + DCT tables -> dct_in -> state ----
    if (tid < 120) *(f4*)(R + tid * 16) = *(const f4*)(seq + (size_t)b * 2400 + 1920 + tid * 4);
    for (int v = tid; v < 310; v += 256)
        ((float*)(R + 2048))[v] = (v < 300) ? dctm[v] : dtail[v - 300];
    __syncthreads();
    for (int v = tid; v < 480; v += 256) {
        int f = v / 10, d = v % 10;
        const float* q = (const float*)R;
        const float* L = (const float*)(R + 2048);
        float a = L[300 + d] * q[9 * 48 + f];
        #pragma unroll
        for (int k = 0; k < 10; ++k) a += L[d * 30 + k] * q[k * 48 + f];
        ((float*)dctf)[f * 12 + d] = a;
    }
    __syncthreads();
    for (int v = tid; v < 384; v += 256) {
        int m = v >> 3, g = v & 7;
        h8 w = (h8)(_Float16)0.0f;
        if (g < 2) {
            #pragma unroll
            for (int j = 0; j < 8; ++j) {
                int d = g * 8 + j;
                if (d < 10) w[j] = (_Float16)((float*)dctf)[m * 12 + d];
            }
        }
        *(h8*)(S + m * 1024 + ((g ^ (m & 7)) << 4)) = w;
    }

    h4 sv[24];
    gcn_layer<2, 0>(S, T, P1,          attp,          gc1_b,        sv, lane, wv, l16, quad);
    gcn_layer<16, 1>(S, T, Pm,          attp + 3072,  gcb_b,        sv, lane, wv, l16, quad);
    gcn_layer<16, 2>(S, T, Pm + 262144, attp + 6144,  gcb_b + 512,  sv, lane, wv, l16, quad);
    gcn_layer<16, 1>(S, T, Pm + 524288, attp + 9216,  gcb_b + 1024, sv, lane, wv, l16, quad);
    gcn_layer<16, 2>(S, T, Pm + 786432, attp + 12288, gcb_b + 1536, sv, lane, wv, l16, quad);

    // ---- L6 (gc7, N=16 padded) + recon ----
    __syncthreads();
    {
        f4 acc[3];
        #pragma unroll
        for (int mt = 0; mt < 3; ++mt) acc[mt] = (f4)0.0f;
        const _Float16* Pb7 = P7 + wv * 2048 + lane * 8;
        #pragma unroll
        for (int ks = 0; ks < 4; ++ks) {
            h8 bfr = *(const h8*)(Pb7 + ks * 512);
            int kh = wv * 128 + ks * 32;
            #pragma unroll
            for (int mt = 0; mt < 3; ++mt) {
                h8 a = *(h8*)(S + (mt * 16 + l16) * 1024 + ((((kh >> 3) + quad) ^ (l16 & 7)) << 4));
                acc[mt] = __builtin_amdgcn_mfma_f32_16x16x32_f16(a, bfr, acc[mt], 0, 0, 0);
            }
        }
        #pragma unroll
        for (int mt = 0; mt < 3; ++mt)
            *(f4*)(R + wv * 3072 + l16 * 192 + (mt * 16 + quad * 4) * 4) = acc[mt];
    }
    __syncthreads();
    if (wv == 0) {
        h4 tw[3]; int ns[3], ms[3];
        #pragma unroll
        for (int q = 0; q < 3; ++q) {
            int idx = lane * 3 + q;
            int n = idx / 12, m0 = (idx % 12) * 4;
            f4 s = *(f4*)(R + n * 192 + m0 * 4);
            s += *(f4*)(R + 3072 + n * 192 + m0 * 4);
            s += *(f4*)(R + 6144 + n * 192 + m0 * 4);
            s += *(f4*)(R + 9216 + n * 192 + m0 * 4);
            h4 h;
            #pragma unroll
            for (int j = 0; j < 4; ++j) h[j] = (_Float16)s[j];
            tw[q] = h; ns[q] = n; ms[q] = m0;
        }
        asm volatile("s_waitcnt lgkmcnt(0)" ::: "memory");
        #pragma unroll
        for (int q = 0; q < 3; ++q) *(h4*)(R + ns[q] * 144 + ms[q] * 2) = tw[q];
        if (lane < 48) {
            int row = lane / 3, s2 = lane % 3;
            *(h8*)(R + row * 144 + 96 + s2 * 16) = (h8)(_Float16)0.0f;
        }
        asm volatile("s_waitcnt lgkmcnt(0)" ::: "memory");
        h8 tf0 = *(h8*)(R + l16 * 144 + quad * 16);
        h8 tf1 = *(h8*)(R + l16 * 144 + 64 + quad * 16);
        const _Float16* a7 = attp + 15360;
        f4 acc2[3];
        #pragma unroll
        for (int it = 0; it < 3; ++it) {
            h8 ab0 = *(const h8*)(a7 + (it * 16 + l16) * 64 + quad * 8);
            h8 ab1 = *(const h8*)(a7 + (it * 16 + l16) * 64 + 32 + quad * 8);
            acc2[it] = __builtin_amdgcn_mfma_f32_16x16x32_f16(tf0, ab0, (f4)0.0f, 0, 0, 0);
            acc2[it] = __builtin_amdgcn_mfma_f32_16x16x32_f16(tf1, ab1, acc2[it], 0, 0, 0);
        }
        char* G = R + 4096;   // 48 x 16 f32
        #pragma unroll
        for (int it = 0; it < 3; ++it) {
            int f = it * 16 + l16;
            #pragma unroll
            for (int j = 0; j < 4; ++j) {
                int c = quad * 4 + j;
                if (c < 10) {
                    float v = acc2[it][j] + gc7_b[c] + ((float*)dctf)[f * 12 + c];
                    *(float*)(G + f * 64 + c * 4) = v;
                }
            }
        }
    }
    __syncthreads();
    {
        char* G = R + 4096;
        for (int v = tid; v < 1440; v += 256) {
            int f = v / 30, t = v % 30;
            float s = 0.f;
            #pragma unroll
            for (int d = 0; d < 10; ++d) s += dctm[d * 30 + t] * *(float*)(G + f * 64 + d * 4);
            fusedb[(size_t)b * 1440 + v] = s;
        }
    }
}

// =============== fused FFC (direct DFT) + MLP head (MFMA) ===============
__launch_bounds__(256, 3)
__global__ void ffc_mlp_kernel(const float* __restrict__ seq,
                               const float* __restrict__ fusedb,
                               const float* __restrict__ wl,
                               const float* __restrict__ wg,
                               const _Float16* __restrict__ Pw1,
                               const _Float16* __restrict__ Pw2,
                               float* __restrict__ out) {
    __shared__ __align__(16) char smem[45312];
    float* ext = (float*)smem;                 // [60][48], dead after fus fill
    float* Xre = (float*)(smem + 11520);       // [48][32]
    float* Xim = (float*)(smem + 17664);       // [48][32]
    float* Yo  = (float*)(smem + 23808);       // [6][16][32]
    _Float16* hlds = (_Float16*)smem;          // [48][264]  (overlays ext/Xre/Xim)
    char* R2 = smem + 25344;                   // 12288 partials (overlays Yo tail)
    _Float16* fus = (_Float16*)(smem + 37632); // [48][72]  (pitch 144 B)
    float* c60 = (float*)(smem + 44544);
    float* s60 = (float*)(smem + 44784);
    float* wls = (float*)(smem + 45024);
    float* wgs = (float*)(smem + 45072);

    const int b = blockIdx.x, tid = threadIdx.x;
    const int lane = tid & 63, wv = tid >> 6;
    const int l16 = lane & 15, quad = lane >> 4;
    const float* s = seq + (size_t)b * TT * FF;

    for (int idx = tid; idx < EXTN * FF; idx += 256) {
        int t = idx / FF, f = idx % FF;
        int ts = t < TT ? t : TT - 1;
        ext[t * FF + f] = s[ts * FF + f];
    }
    if (tid < 60) { c60[tid] = cospif(tid / 30.0f); s60[tid] = sinpif(tid / 30.0f); }
    if (tid >= 64 && tid < 73) wls[tid - 64] = wl[tid - 64];
    if (tid >= 128 && tid < 164) wgs[tid - 128] = wg[tid - 128];
    __syncthreads();
    for (int idx = tid; idx < FF * NFREQ; idx += 256) {
        int f = idx % FF, k = idx / FF;
        float re = 0.f, im = 0.f;
        int kt = 0;
        for (int t = 0; t < EXTN; ++t) {
            float v = ext[t * FF + f];
            re += v * c60[kt];
            im -= v * s60[kt];
            kt += k; kt = (kt >= 60) ? kt - 60 : kt;
        }
        Xre[f * 32 + k] = re; Xim[f * 32 + k] = im;
    }
    __syncthreads();
    for (int idx = tid; idx < 6 * 16 * NFREQ; idx += 256) {
        int k = idx % NFREQ; int g = (idx / NFREQ) % 16; int o = idx / (NFREQ * 16);
        float v = wgs[o * 6 + 0] * Xre[g * 32 + k]        + wgs[o * 6 + 1] * Xre[(16 + g) * 32 + k]
                + wgs[o * 6 + 2] * Xre[(32 + g) * 32 + k] + wgs[o * 6 + 3] * Xim[g * 32 + k]
                + wgs[o * 6 + 4] * Xim[(16 + g) * 32 + k] + wgs[o * 6 + 5] * Xim[(32 + g) * 32 + k];
        Yo[(o * 16 + g) * 32 + k] = fmaxf(v, 0.f);
    }
    __syncthreads();
    // ---- build fus (48 x 64 f16, pitch 72 halves): recon (global) + ffc + zero pad ----
    for (int v = tid; v < 1440; v += 256) {
        int f = v / 30, t = v % 30;
        fus[f * 72 + t] = (_Float16)fusedb[(size_t)b * 1440 + v];
    }
    for (int v = tid; v < 1152; v += 256) {
        int f = v / 24, t = 40 + v % 24;
        fus[f * 72 + t] = (_Float16)0.0f;
    }
    for (int idx = tid; idx < 480; idx += 256) {
        int t = idx % 10; int g = (idx / 10) % 16; int c = idx / 160;
        float acc = Yo[(c * 16 + g) * 32 + 0] + Yo[(c * 16 + g) * 32 + 30] * ((t & 1) ? -1.f : 1.f);
        float s2 = 0.f;
        int kt = t;
        for (int k = 1; k < 30; ++k) {
            s2 += Yo[(c * 16 + g) * 32 + k] * c60[kt] - Yo[((c + 3) * 16 + g) * 32 + k] * s60[kt];
            kt += t; kt = (kt >= 60) ? kt - 60 : kt;
        }
        acc = (acc + 2.f * s2) * (1.0f / 60.0f);
        float loc = wls[c * 3 + 0] * ext[t * FF + g] + wls[c * 3 + 1] * ext[t * FF + 16 + g]
                  + wls[c * 3 + 2] * ext[t * FF + 32 + g];
        int f = c * 16 + g;
        fus[f * 72 + 30 + t] = (_Float16)(acc + loc);
    }
    __syncthreads();
    // ---- mlp1: h = relu(fus @ w1^T) via MFMA; per wave o-slice 64 ----
    f4 acc1[3][4];
    #pragma unroll
    for (int mt = 0; mt < 3; ++mt)
        #pragma unroll
        for (int nt = 0; nt < 4; ++nt) acc1[mt][nt] = (f4)0.0f;
    #pragma unroll
    for (int ks = 0; ks < 2; ++ks) {
        h8 af[3], bf[4];
        #pragma unroll
        for (int mt = 0; mt < 3; ++mt)
            af[mt] = *(h8*)((char*)fus + (mt * 16 + l16) * 144 + ks * 64 + quad * 16);
        #pragma unroll
        for (int nt = 0; nt < 4; ++nt)
            bf[nt] = *(const h8*)(Pw1 + (size_t)(((wv * 4 + nt) * 2 + ks) * 512) + lane * 8);
        #pragma unroll
        for (int mt = 0; mt < 3; ++mt)
            #pragma unroll
            for (int nt = 0; nt < 4; ++nt)
                acc1[mt][nt] = __builtin_amdgcn_mfma_f32_16x16x32_f16(af[mt], bf[nt], acc1[mt][nt], 0, 0, 0);
    }
    __syncthreads();   // ext/Xre/Xim/Yo dead -> hlds region free
    #pragma unroll
    for (int mt = 0; mt < 3; ++mt)
        #pragma unroll
        for (int nt = 0; nt < 4; ++nt) {
            int o = wv * 64 + nt * 16 + l16;
            #pragma unroll
            for (int j = 0; j < 4; ++j) {
                int f = mt * 16 + quad * 4 + j;
                hlds[f * 264 + o] = (_Float16)fmaxf(acc1[mt][nt][j], 0.f);
            }
        }
    __syncthreads();
    // ---- mlp2: out^T[t][f] = w2 @ h^T via MFMA, k split across waves ----
    f4 acc2[3];
    #pragma unroll
    for (int nt3 = 0; nt3 < 3; ++nt3) acc2[nt3] = (f4)0.0f;
    #pragma unroll
    for (int ss = 0; ss < 2; ++ss) {
        int ks = wv * 2 + ss;
        h8 aw = *(const h8*)(Pw2 + (size_t)ks * 512 + lane * 8);
        #pragma unroll
        for (int nt3 = 0; nt3 < 3; ++nt3) {
            h8 bh = *(h8*)((char*)hlds + (nt3 * 16 + l16) * 528 + ks * 64 + quad * 16);
            acc2[nt3] = __builtin_amdgcn_mfma_f32_16x16x32_f16(aw, bh, acc2[nt3], 0, 0, 0);
        }
    }
    #pragma unroll
    for (int nt3 = 0; nt3 < 3; ++nt3)
        *(f4*)(R2 + wv * 3072 + (nt3 * 16 + l16) * 64 + quad * 16) = acc2[nt3];
    __syncthreads();
    for (int v = tid; v < 768; v += 256) {
        int f = v >> 4, t = v & 15;
        float sm = 0.f;
        #pragma unroll
        for (int w4 = 0; w4 < 4; ++w4) sm += *(float*)(R2 + w4 * 3072 + f * 64 + t * 4);
        if (t < 10) out[(size_t)b * 480 + t * 48 + f] = sm;
    }
}

extern "C" void kernel_launch(void* const* d_in, const int* in_sizes, int n_in,
                              void* d_out, int out_size, void* d_ws, size_t ws_size,
                              hipStream_t stream) {
    (void)in_sizes; (void)n_in; (void)out_size;
    const float* seq     = (const float*)d_in[0];
    // d_in[1..4] = wq1,wq2,wk1,wk2 — dead (attention branch sliced away by combined[:,:,:10])
    const float* gc1_w   = (const float*)d_in[5];
    const float* gc1_att = (const float*)d_in[6];
    const float* gc1_b   = (const float*)d_in[7];
    const float* gcb_w   = (const float*)d_in[8];
    const float* gcb_att = (const float*)d_in[9];
    const float* gcb_b   = (const float*)d_in[10];
    const float* gc7_w   = (const float*)d_in[11];
    const float* gc7_att = (const float*)d_in[12];
    const float* gc7_b   = (const float*)d_in[13];
    const float* mlp_w1  = (const float*)d_in[14];
    const float* mlp_w2  = (const float*)d_in[15];
    const float* ffc_wl  = (const float*)d_in[16];
    const float* ffc_wg  = (const float*)d_in[17];
    float* out = (float*)d_out;
    char* ws = (char*)d_ws;

    // fixed region (16B-aligned slabs)
    float*    dctm  = (float*)ws;                      // 900 f
    float*    dtail = dctm + 900;                      // 10 f
    char*     p0    = ws + 4096;
    _Float16* Pm   = (_Float16*)p0;   p0 += 4 * 262144 * 2;   // packed big-layer weights
    _Float16* P1   = (_Float16*)p0;   p0 += 32768 * 2;
    _Float16* P7   = (_Float16*)p0;   p0 += 8192 * 2;
    _Float16* Pw1  = (_Float16*)p0;   p0 += 16384 * 2;
    _Float16* Pw2  = (_Float16*)p0;   p0 += 4096 * 2;
    _Float16* attp = (_Float16*)p0;   p0 += 18432 * 2;
    const size_t fixed_bytes = (size_t)(p0 - ws);

    const size_t per_batch = 5760;   // fusedb: 48 x 30 f32
    size_t avail = (ws_size > fixed_bytes) ? (ws_size - fixed_bytes) : 0;
    int nc = 1;
    while ((size_t)(BB / nc) * per_batch > avail && nc < 64) nc *= 2;
    int Bc = BB / nc;
    float* fusedb = (float*)(ws + fixed_bytes);

    prep_kernel<<<618, 256, 0, stream>>>(gcb_w, Pm, gc1_w, P1, gc7_w, P7,
                                         mlp_w1, Pw1, mlp_w2, Pw2,
                                         gc1_att, gcb_att, gc7_att, attp, dctm, dtail);

    for (int ci = 0; ci < nc; ++ci) {
        const float* seqc = seq + (size_t)ci * Bc * TT * FF;
        float* outc = out + (size_t)ci * Bc * 480;
        gcn_fused_kernel<<<Bc, 256, 0, stream>>>(seqc, P1, Pm, P7, attp,
                                                 gc1_b, gcb_b, gc7_b, dctm, dtail, fusedb);
        ffc_mlp_kernel<<<Bc, 256, 0, stream>>>(seqc, fusedb, ffc_wl, ffc_wg, Pw1, Pw2, outc);
    }
}

// Round 9
// 306.943 us; speedup vs baseline: 1.0231x; 1.0231x over previous
//
#include <hip/hip_runtime.h>
#include <math.h>

#define BB 1024
#define TT 50
#define FF 48
#define EXTN 60
#define NFREQ 31

typedef _Float16 h8 __attribute__((ext_vector_type(8)));
typedef _Float16 h4 __attribute__((ext_vector_type(4)));
typedef float f4 __attribute__((ext_vector_type(4)));

__device__ __forceinline__ float fast_tanh(float x) {
    float e = __expf(2.0f * x);
    return 1.0f - 2.0f * __builtin_amdgcn_rcpf(e + 1.0f);
}

// =============== prep: pack ALL weights into MFMA-fragment order ===============
// Main P layout (per layer): tile t8 = (wv*16+ks)*8+nt ; P[t8*512 + lane*8 + j] =
//   W[k = ks*32+(lane>>4)*8+j][n = wv*128+nt*16+(lane&15)]  -> frag load = base+lane*16.
__global__ void prep_kernel(const float* __restrict__ gcb_w, _Float16* __restrict__ P,
                            const float* __restrict__ gc1_w, _Float16* __restrict__ P1,
                            const float* __restrict__ gc7_w, _Float16* __restrict__ P7,
                            const float* __restrict__ mlp_w1, _Float16* __restrict__ Pw1,
                            const float* __restrict__ mlp_w2, _Float16* __restrict__ Pw2,
                            const float* __restrict__ gc1_att, const float* __restrict__ gcb_att,
                            const float* __restrict__ gc7_att, _Float16* __restrict__ attp,
                            float* __restrict__ dctm, float* __restrict__ dtail) {
    int blk = blockIdx.x, tid = threadIdx.x;
    const _Float16 HZ = (_Float16)0.0f;
    if (blk < 512) {                    // big-layer weights, 4 x 512KB
        int z = blk >> 7;
        int idx = ((blk & 127) << 8) | tid;
        int lane = idx & 63, t8 = idx >> 6;
        int nt = t8 & 7, kw = t8 >> 3;
        int ks = kw & 15, wv = kw >> 4;
        int n = wv * 128 + nt * 16 + (lane & 15);
        int k0 = ks * 32 + (lane >> 4) * 8;
        const float* src = gcb_w + (size_t)z * 262144 + n;
        h8 v;
        #pragma unroll
        for (int j = 0; j < 8; ++j) v[j] = (_Float16)src[(size_t)(k0 + j) * 512];
        *(h8*)(P + (size_t)z * 262144 + (size_t)idx * 8) = v;
    } else if (blk < 528) {             // L1 weights (K=64 padded)
        int idx = ((blk - 512) << 8) | tid;
        int lane = idx & 63, t8 = idx >> 6;
        int nt = t8 & 7, kw = t8 >> 3;
        int ks = kw & 1, wv = kw >> 1;
        int n = wv * 128 + nt * 16 + (lane & 15);
        int k0 = ks * 32 + (lane >> 4) * 8;
        h8 v;
        #pragma unroll
        for (int j = 0; j < 8; ++j) v[j] = (k0 + j < 10) ? (_Float16)gc1_w[(k0 + j) * 512 + n] : HZ;
        *(h8*)(P1 + (size_t)idx * 8) = v;
    } else if (blk < 532) {             // L6 weights (N=16 padded, k split across waves)
        int idx = ((blk - 528) << 8) | tid;
        int lane = idx & 63, t8 = idx >> 6;     // 0..15
        int ks = t8 & 3, wv = t8 >> 2;
        int n = lane & 15;
        int k0 = wv * 128 + ks * 32 + (lane >> 4) * 8;
        h8 v;
        #pragma unroll
        for (int j = 0; j < 8; ++j) v[j] = (n < 10) ? (_Float16)gc7_w[(k0 + j) * 10 + n] : HZ;
        *(h8*)(P7 + (size_t)idx * 8) = v;
    } else if (blk < 540) {             // mlp w1 as B-frags (K=64 padded)
        int idx = ((blk - 532) << 8) | tid;     // 0..2047
        int lane = idx & 63, t8 = idx >> 6;     // 0..31 = ((wv*4+nt)*2+ks)
        int ks = t8 & 1, q = t8 >> 1;
        int nt = q & 3, wv = q >> 2;
        int o = wv * 64 + nt * 16 + (lane & 15);
        int k0 = ks * 32 + (lane >> 4) * 8;
        h8 v;
        #pragma unroll
        for (int j = 0; j < 8; ++j) v[j] = (k0 + j < 40) ? (_Float16)mlp_w1[o * 40 + k0 + j] : HZ;
        *(h8*)(Pw1 + (size_t)idx * 8) = v;
    } else if (blk < 542) {             // mlp w2 as A-frags (M=16 padded rows t)
        int idx = ((blk - 540) << 8) | tid;     // 0..511
        int lane = idx & 63, ks = idx >> 6;     // 0..7
        int m = lane & 15;
        int k0 = ks * 32 + (lane >> 4) * 8;
        h8 v;
        #pragma unroll
        for (int j = 0; j < 8; ++j) v[j] = (m < 10) ? (_Float16)mlp_w2[m * 256 + k0 + j] : HZ;
        *(h8*)(Pw2 + (size_t)idx * 8) = v;
    } else if (blk < 614) {             // att matrices, k zero-padded to 64
        int idx = (blk - 542) * 256 + tid;
        if (idx < 18432) {
            int l = idx / 3072, r = (idx % 3072) / 64, m = idx & 63;
            float v = 0.f;
            if (m < 48) {
                v = (l == 0) ? gc1_att[r * 48 + m]
                  : (l <= 4) ? gcb_att[(l - 1) * 2304 + r * 48 + m]
                             : gc7_att[r * 48 + m];
            }
            attp[idx] = (_Float16)v;
        }
    } else {                            // DCT tables
        int idx = (blk - 614) * 256 + tid;
        if (idx < 900) {
            int d = idx / 30, k = idx % 30;
            double w = (d == 0) ? sqrt(1.0 / 30.0) : sqrt(2.0 / 30.0);
            dctm[idx] = (float)(w * cos(M_PI * (k + 0.5) * d / 30.0));
        } else if (idx < 910) {
            int d = idx - 900;
            double w = (d == 0) ? sqrt(1.0 / 30.0) : sqrt(2.0 / 30.0);
            double s = 0.0;
            for (int k = 10; k < 30; ++k) s += w * cos(M_PI * (k + 0.5) * d / 30.0);
            dtail[d] = (float)s;
        }
    }
}

// =============== one GCN layer on LDS-resident state, packed weights ===============
// State S: 48 rows x 1024 B (512 f16), 16B granules XOR-swizzled by (row&7).
// K-loop: B(weight) frags double-buffered in registers (depth 1); A frags (LDS) just-in-time.
// att frags loaded in the epilogue (B-frags dead there) to stay under the 256-reg budget.
// MODE 0: tanh. MODE 1: tanh + save old state into sv. MODE 2: tanh + add sv.
template<int KSTEPS, int MODE>
__device__ __forceinline__ void gcn_layer(char* S, char* T,
        const _Float16* __restrict__ Pw, const _Float16* __restrict__ attp,
        const float* __restrict__ bias, h4* sv,
        int lane, int wv, int l16, int quad) {
    f4 acc[3][8];
    #pragma unroll
    for (int mt = 0; mt < 3; ++mt)
        #pragma unroll
        for (int nt = 0; nt < 8; ++nt) acc[mt][nt] = (f4)0.0f;

    const _Float16* Pb = Pw + (size_t)wv * (KSTEPS * 8 * 512) + lane * 8;
    const int xm = l16 & 7;

    h8 bcur[8], bnxt[8];
    #pragma unroll
    for (int nt = 0; nt < 8; ++nt) bcur[nt] = *(const h8*)(Pb + nt * 512);
    __syncthreads();   // state ready

    #pragma unroll
    for (int ks = 0; ks < KSTEPS; ++ks) {
        if (ks + 1 < KSTEPS) {
            #pragma unroll
            for (int nt = 0; nt < 8; ++nt)
                bnxt[nt] = *(const h8*)(Pb + ((ks + 1) * 8 + nt) * 512);
        }
        h8 a[3];
        #pragma unroll
        for (int mt = 0; mt < 3; ++mt)
            a[mt] = *(h8*)(S + (mt * 16 + l16) * 1024 + (((ks * 4 + quad) ^ xm) << 4));
        #pragma unroll
        for (int mt = 0; mt < 3; ++mt)
            #pragma unroll
            for (int nt = 0; nt < 8; ++nt)
                acc[mt][nt] = __builtin_amdgcn_mfma_f32_16x16x32_f16(a[mt], bcur[nt], acc[mt][nt], 0, 0, 0);
        #pragma unroll
        for (int nt = 0; nt < 8; ++nt) bcur[nt] = bnxt[nt];
    }
    __syncthreads();   // all reads done; epilogue may overwrite state

    // att B-frags (rows i, k=m zero-padded to 64) — loaded now that b-frags are dead
    h8 ab[3][2];
    #pragma unroll
    for (int it = 0; it < 3; ++it)
        #pragma unroll
        for (int ks = 0; ks < 2; ++ks)
            ab[it][ks] = *(const h8*)(attp + (it * 16 + l16) * 64 + ks * 32 + quad * 8);

    if (lane < 48) {
        int row = lane / 3, s = lane % 3;
        *(h8*)(T + row * 144 + 96 + s * 16) = (h8)(_Float16)0.0f;
    }

    #pragma unroll
    for (int nt = 0; nt < 8; ++nt) {
        #pragma unroll
        for (int mt = 0; mt < 3; ++mt) {
            h4 hv;
            #pragma unroll
            for (int j = 0; j < 4; ++j) hv[j] = (_Float16)acc[mt][nt][j];
            *(h4*)(T + l16 * 144 + (mt * 16 + quad * 4) * 2) = hv;
        }
        asm volatile("s_waitcnt lgkmcnt(0)" ::: "memory");
        h8 tf0 = *(h8*)(T + l16 * 144 + quad * 16);
        h8 tf1 = *(h8*)(T + l16 * 144 + 64 + quad * 16);
        f4 acc2[3];
        #pragma unroll
        for (int it = 0; it < 3; ++it) {
            acc2[it] = __builtin_amdgcn_mfma_f32_16x16x32_f16(tf0, ab[it][0], (f4)0.0f, 0, 0, 0);
            acc2[it] = __builtin_amdgcn_mfma_f32_16x16x32_f16(tf1, ab[it][1], acc2[it], 0, 0, 0);
        }
        const int c0 = wv * 128 + nt * 16 + quad * 4;
        const f4 bv = *(const f4*)(bias + c0);
        #pragma unroll
        for (int it = 0; it < 3; ++it) {
            int f = it * 16 + l16;
            char* sp = S + f * 1024 + (((c0 >> 3) ^ (f & 7)) << 4) + ((c0 & 7) << 1);
            if (MODE == 1) sv[nt * 3 + it] = *(h4*)sp;
            h4 o;
            #pragma unroll
            for (int j = 0; j < 4; ++j) {
                float v = fast_tanh(acc2[it][j] + bv[j]);
                if (MODE == 2) v += (float)sv[nt * 3 + it][j];
                o[j] = (_Float16)v;
            }
            *(h4*)sp = o;
        }
    }
}

// =============== fused GCN: dct_in + L1..L6 + recon, one WG per batch ===============
__launch_bounds__(256, 2)
__global__ void gcn_fused_kernel(const float* __restrict__ seq,
                                 const _Float16* __restrict__ P1,
                                 const _Float16* __restrict__ Pm,
                                 const _Float16* __restrict__ P7,
                                 const _Float16* __restrict__ attp,
                                 const float* __restrict__ gc1_b,
                                 const float* __restrict__ gcb_b,
                                 const float* __restrict__ gc7_b,
                                 const float* __restrict__ dctm,
                                 const float* __restrict__ dtail,
                                 float* __restrict__ fusedb) {
    __shared__ __align__(16) char smem[63744];
    char* S    = smem;              // 48 x 1024 state
    char* R    = smem + 49152;      // 12288: staging / transit / L6 partials / G
    char* dctf = smem + 61440;      // 48 x 12 f32 (dct_in, resid for L6)
    const int tid = threadIdx.x, lane = tid & 63, wv = tid >> 6;
    const int l16 = lane & 15, quad = lane >> 4;
    const int b = blockIdx.x;
    char* T = R + wv * 2304;

    // ---- prologue: seq rows 40..49 + DCT tables -> dct_in -> state ----
    if (tid < 120) *(f4*)(R + tid * 16) = *(const f4*)(seq + (size_t)b * 2400 + 1920 + tid * 4);
    for (int v = tid; v < 310; v += 256)
        ((float*)(R + 2048))[v] = (v < 300) ? dctm[v] : dtail[v - 300];
    __syncthreads();
    for (int v = tid; v < 480; v += 256) {
        int f = v / 10, d = v % 10;
        const float* q = (const float*)R;
        const float* L = (const float*)(R + 2048);
        float a = L[300 + d] * q[9 * 48 + f];
        #pragma unroll
        for (int k = 0; k < 10; ++k) a += L[d * 30 + k] * q[k * 48 + f];
        ((float*)dctf)[f * 12 + d] = a;
    }
    __syncthreads();
    for (int v = tid; v < 384; v += 256) {
        int m = v >> 3, g = v & 7;
        h8 w = (h8)(_Float16)0.0f;
        if (g < 2) {
            #pragma unroll
            for (int j = 0; j < 8; ++j) {
                int d = g * 8 + j;
                if (d < 10) w[j] = (_Float16)((float*)dctf)[m * 12 + d];
            }
        }
        *(h8*)(S + m * 1024 + ((g ^ (m & 7)) << 4)) = w;
    }

    h4 sv[24];
    gcn_layer<2, 0>(S, T, P1,          attp,          gc1_b,        sv, lane, wv, l16, quad);
    gcn_layer<16, 1>(S, T, Pm,          attp + 3072,  gcb_b,        sv, lane, wv, l16, quad);
    gcn_layer<16, 2>(S, T, Pm + 262144, attp + 6144,  gcb_b + 512,  sv, lane, wv, l16, quad);
    gcn_layer<16, 1>(S, T, Pm + 524288, attp + 9216,  gcb_b + 1024, sv, lane, wv, l16, quad);
    gcn_layer<16, 2>(S, T, Pm + 786432, attp + 12288, gcb_b + 1536, sv, lane, wv, l16, quad);

    // ---- L6 (gc7, N=16 padded) + recon ----
    __syncthreads();
    {
        f4 acc[3];
        #pragma unroll
        for (int mt = 0; mt < 3; ++mt) acc[mt] = (f4)0.0f;
        const _Float16* Pb7 = P7 + wv * 2048 + lane * 8;
        #pragma unroll
        for (int ks = 0; ks < 4; ++ks) {
            h8 bfr = *(const h8*)(Pb7 + ks * 512);
            int kh = wv * 128 + ks * 32;
            #pragma unroll
            for (int mt = 0; mt < 3; ++mt) {
                h8 a = *(h8*)(S + (mt * 16 + l16) * 1024 + ((((kh >> 3) + quad) ^ (l16 & 7)) << 4));
                acc[mt] = __builtin_amdgcn_mfma_f32_16x16x32_f16(a, bfr, acc[mt], 0, 0, 0);
            }
        }
        #pragma unroll
        for (int mt = 0; mt < 3; ++mt)
            *(f4*)(R + wv * 3072 + l16 * 192 + (mt * 16 + quad * 4) * 4) = acc[mt];
    }
    __syncthreads();
    if (wv == 0) {
        h4 tw[3]; int ns[3], ms[3];
        #pragma unroll
        for (int q = 0; q < 3; ++q) {
            int idx = lane * 3 + q;
            int n = idx / 12, m0 = (idx % 12) * 4;
            f4 s = *(f4*)(R + n * 192 + m0 * 4);
            s += *(f4*)(R + 3072 + n * 192 + m0 * 4);
            s += *(f4*)(R + 6144 + n * 192 + m0 * 4);
            s += *(f4*)(R + 9216 + n * 192 + m0 * 4);
            h4 h;
            #pragma unroll
            for (int j = 0; j < 4; ++j) h[j] = (_Float16)s[j];
            tw[q] = h; ns[q] = n; ms[q] = m0;
        }
        asm volatile("s_waitcnt lgkmcnt(0)" ::: "memory");
        #pragma unroll
        for (int q = 0; q < 3; ++q) *(h4*)(R + ns[q] * 144 + ms[q] * 2) = tw[q];
        if (lane < 48) {
            int row = lane / 3, s2 = lane % 3;
            *(h8*)(R + row * 144 + 96 + s2 * 16) = (h8)(_Float16)0.0f;
        }
        asm volatile("s_waitcnt lgkmcnt(0)" ::: "memory");
        h8 tf0 = *(h8*)(R + l16 * 144 + quad * 16);
        h8 tf1 = *(h8*)(R + l16 * 144 + 64 + quad * 16);
        const _Float16* a7 = attp + 15360;
        f4 acc2[3];
        #pragma unroll
        for (int it = 0; it < 3; ++it) {
            h8 ab0 = *(const h8*)(a7 + (it * 16 + l16) * 64 + quad * 8);
            h8 ab1 = *(const h8*)(a7 + (it * 16 + l16) * 64 + 32 + quad * 8);
            acc2[it] = __builtin_amdgcn_mfma_f32_16x16x32_f16(tf0, ab0, (f4)0.0f, 0, 0, 0);
            acc2[it] = __builtin_amdgcn_mfma_f32_16x16x32_f16(tf1, ab1, acc2[it], 0, 0, 0);
        }
        char* G = R + 4096;   // 48 x 16 f32
        #pragma unroll
        for (int it = 0; it < 3; ++it) {
            int f = it * 16 + l16;
            #pragma unroll
            for (int j = 0; j < 4; ++j) {
                int c = quad * 4 + j;
                if (c < 10) {
                    float v = acc2[it][j] + gc7_b[c] + ((float*)dctf)[f * 12 + c];
                    *(float*)(G + f * 64 + c * 4) = v;
                }
            }
        }
    }
    __syncthreads();
    {
        char* G = R + 4096;
        for (int v = tid; v < 1440; v += 256) {
            int f = v / 30, t = v % 30;
            float s = 0.f;
            #pragma unroll
            for (int d = 0; d < 10; ++d) s += dctm[d * 30 + t] * *(float*)(G + f * 64 + d * 4);
            fusedb[(size_t)b * 1440 + v] = s;
        }
    }
}

// =============== fused FFC (direct DFT) + MLP head (MFMA) ===============
__launch_bounds__(256, 3)
__global__ void ffc_mlp_kernel(const float* __restrict__ seq,
                               const float* __restrict__ fusedb,
                               const float* __restrict__ wl,
                               const float* __restrict__ wg,
                               const _Float16* __restrict__ Pw1,
                               const _Float16* __restrict__ Pw2,
                               float* __restrict__ out) {
    __shared__ __align__(16) char smem[45312];
    float* ext = (float*)smem;                 // [60][48], dead after fus fill
    float* Xre = (float*)(smem + 11520);       // [48][32]
    float* Xim = (float*)(smem + 17664);       // [48][32]
    float* Yo  = (float*)(smem + 23808);       // [6][16][32]
    _Float16* hlds = (_Float16*)smem;          // [48][264]  (overlays ext/Xre/Xim)
    char* R2 = smem + 25344;                   // 12288 partials (overlays Yo tail)
    _Float16* fus = (_Float16*)(smem + 37632); // [48][72]  (pitch 144 B)
    float* c60 = (float*)(smem + 44544);
    float* s60 = (float*)(smem + 44784);
    float* wls = (float*)(smem + 45024);
    float* wgs = (float*)(smem + 45072);

    const int b = blockIdx.x, tid = threadIdx.x;
    const int lane = tid & 63, wv = tid >> 6;
    const int l16 = lane & 15, quad = lane >> 4;
    const float* s = seq + (size_t)b * TT * FF;

    for (int idx = tid; idx < EXTN * FF; idx += 256) {
        int t = idx / FF, f = idx % FF;
        int ts = t < TT ? t : TT - 1;
        ext[t * FF + f] = s[ts * FF + f];
    }
    if (tid < 60) { c60[tid] = cospif(tid / 30.0f); s60[tid] = sinpif(tid / 30.0f); }
    if (tid >= 64 && tid < 73) wls[tid - 64] = wl[tid - 64];
    if (tid >= 128 && tid < 164) wgs[tid - 128] = wg[tid - 128];
    __syncthreads();
    for (int idx = tid; idx < FF * NFREQ; idx += 256) {
        int f = idx % FF, k = idx / FF;
        float re = 0.f, im = 0.f;
        int kt = 0;
        for (int t = 0; t < EXTN; ++t) {
            float v = ext[t * FF + f];
            re += v * c60[kt];
            im -= v * s60[kt];
            kt += k; kt = (kt >= 60) ? kt - 60 : kt;
        }
        Xre[f * 32 + k] = re; Xim[f * 32 + k] = im;
    }
    __syncthreads();
    for (int idx = tid; idx < 6 * 16 * NFREQ; idx += 256) {
        int k = idx % NFREQ; int g = (idx / NFREQ) % 16; int o = idx / (NFREQ * 16);
        float v = wgs[o * 6 + 0] * Xre[g * 32 + k]        + wgs[o * 6 + 1] * Xre[(16 + g) * 32 + k]
                + wgs[o * 6 + 2] * Xre[(32 + g) * 32 + k] + wgs[o * 6 + 3] * Xim[g * 32 + k]
                + wgs[o * 6 + 4] * Xim[(16 + g) * 32 + k] + wgs[o * 6 + 5] * Xim[(32 + g) * 32 + k];
        Yo[(o * 16 + g) * 32 + k] = fmaxf(v, 0.f);
    }
    __syncthreads();
    // ---- build fus (48 x 64 f16, pitch 72 halves): recon (global) + ffc + zero pad ----
    for (int v = tid; v < 1440; v += 256) {
        int f = v / 30, t = v % 30;
        fus[f * 72 + t] = (_Float16)fusedb[(size_t)b * 1440 + v];
    }
    for (int v = tid; v < 1152; v += 256) {
        int f = v / 24, t = 40 + v % 24;
        fus[f * 72 + t] = (_Float16)0.0f;
    }
    for (int idx = tid; idx < 480; idx += 256) {
        int t = idx % 10; int g = (idx / 10) % 16; int c = idx / 160;
        float acc = Yo[(c * 16 + g) * 32 + 0] + Yo[(c * 16 + g) * 32 + 30] * ((t & 1) ? -1.f : 1.f);
        float s2 = 0.f;
        int kt = t;
        for (int k = 1; k < 30; ++k) {
            s2 += Yo[(c * 16 + g) * 32 + k] * c60[kt] - Yo[((c + 3) * 16 + g) * 32 + k] * s60[kt];
            kt += t; kt = (kt >= 60) ? kt - 60 : kt;
        }
        acc = (acc + 2.f * s2) * (1.0f / 60.0f);
        float loc = wls[c * 3 + 0] * ext[t * FF + g] + wls[c * 3 + 1] * ext[t * FF + 16 + g]
                  + wls[c * 3 + 2] * ext[t * FF + 32 + g];
        int f = c * 16 + g;
        fus[f * 72 + 30 + t] = (_Float16)(acc + loc);
    }
    __syncthreads();
    // ---- mlp1: h = relu(fus @ w1^T) via MFMA; per wave o-slice 64 ----
    f4 acc1[3][4];
    #pragma unroll
    for (int mt = 0; mt < 3; ++mt)
        #pragma unroll
        for (int nt = 0; nt < 4; ++nt) acc1[mt][nt] = (f4)0.0f;
    #pragma unroll
    for (int ks = 0; ks < 2; ++ks) {
        h8 af[3], bf[4];
        #pragma unroll
        for (int mt = 0; mt < 3; ++mt)
            af[mt] = *(h8*)((char*)fus + (mt * 16 + l16) * 144 + ks * 64 + quad * 16);
        #pragma unroll
        for (int nt = 0; nt < 4; ++nt)
            bf[nt] = *(const h8*)(Pw1 + (size_t)(((wv * 4 + nt) * 2 + ks) * 512) + lane * 8);
        #pragma unroll
        for (int mt = 0; mt < 3; ++mt)
            #pragma unroll
            for (int nt = 0; nt < 4; ++nt)
                acc1[mt][nt] = __builtin_amdgcn_mfma_f32_16x16x32_f16(af[mt], bf[nt], acc1[mt][nt], 0, 0, 0);
    }
    __syncthreads();   // ext/Xre/Xim/Yo dead -> hlds region free
    #pragma unroll
    for (int mt = 0; mt < 3; ++mt)
        #pragma unroll
        for (int nt = 0; nt < 4; ++nt) {
            int o = wv * 64 + nt * 16 + l16;
            #pragma unroll
            for (int j = 0; j < 4; ++j) {
                int f = mt * 16 + quad * 4 + j;
                hlds[f * 264 + o] = (_Float16)fmaxf(acc1[mt][nt][j], 0.f);
            }
        }
    __syncthreads();
    // ---- mlp2: out^T[t][f] = w2 @ h^T via MFMA, k split across waves ----
    f4 acc2[3];
    #pragma unroll
    for (int nt3 = 0; nt3 < 3; ++nt3) acc2[nt3] = (f4)0.0f;
    #pragma unroll
    for (int ss = 0; ss < 2; ++ss) {
        int ks = wv * 2 + ss;
        h8 aw = *(const h8*)(Pw2 + (size_t)ks * 512 + lane * 8);
        #pragma unroll
        for (int nt3 = 0; nt3 < 3; ++nt3) {
            h8 bh = *(h8*)((char*)hlds + (nt3 * 16 + l16) * 528 + ks * 64 + quad * 16);
            acc2[nt3] = __builtin_amdgcn_mfma_f32_16x16x32_f16(aw, bh, acc2[nt3], 0, 0, 0);
        }
    }
    #pragma unroll
    for (int nt3 = 0; nt3 < 3; ++nt3)
        *(f4*)(R2 + wv * 3072 + (nt3 * 16 + l16) * 64 + quad * 16) = acc2[nt3];
    __syncthreads();
    for (int v = tid; v < 768; v += 256) {
        int f = v >> 4, t = v & 15;
        float sm = 0.f;
        #pragma unroll
        for (int w4 = 0; w4 < 4; ++w4) sm += *(float*)(R2 + w4 * 3072 + f * 64 + t * 4);
        if (t < 10) out[(size_t)b * 480 + t * 48 + f] = sm;
    }
}

extern "C" void kernel_launch(void* const* d_in, const int* in_sizes, int n_in,
                              void* d_out, int out_size, void* d_ws, size_t ws_size,
                              hipStream_t stream) {
    (void)in_sizes; (void)n_in; (void)out_size;
    const float* seq     = (const float*)d_in[0];
    // d_in[1..4] = wq1,wq2,wk1,wk2 — dead (attention branch sliced away by combined[:,:,:10])
    const float* gc1_w   = (const float*)d_in[5];
    const float* gc1_att = (const float*)d_in[6];
    const float* gc1_b   = (const float*)d_in[7];
    const float* gcb_w   = (const float*)d_in[8];
    const float* gcb_att = (const float*)d_in[9];
    const float* gcb_b   = (const float*)d_in[10];
    const float* gc7_w   = (const float*)d_in[11];
    const float* gc7_att = (const float*)d_in[12];
    const float* gc7_b   = (const float*)d_in[13];
    const float* mlp_w1  = (const float*)d_in[14];
    const float* mlp_w2  = (const float*)d_in[15];
    const float* ffc_wl  = (const float*)d_in[16];
    const float* ffc_wg  = (const float*)d_in[17];
    float* out = (float*)d_out;
    char* ws = (char*)d_ws;

    // fixed region (16B-aligned slabs)
    float*    dctm  = (float*)ws;                      // 900 f
    float*    dtail = dctm + 900;                      // 10 f
    char*     p0    = ws + 4096;
    _Float16* Pm   = (_Float16*)p0;   p0 += 4 * 262144 * 2;   // packed big-layer weights
    _Float16* P1   = (_Float16*)p0;   p0 += 32768 * 2;
    _Float16* P7   = (_Float16*)p0;   p0 += 8192 * 2;
    _Float16* Pw1  = (_Float16*)p0;   p0 += 16384 * 2;
    _Float16* Pw2  = (_Float16*)p0;   p0 += 4096 * 2;
    _Float16* attp = (_Float16*)p0;   p0 += 18432 * 2;
    const size_t fixed_bytes = (size_t)(p0 - ws);

    const size_t per_batch = 5760;   // fusedb: 48 x 30 f32
    size_t avail = (ws_size > fixed_bytes) ? (ws_size - fixed_bytes) : 0;
    int nc = 1;
    while ((size_t)(BB / nc) * per_batch > avail && nc < 64) nc *= 2;
    int Bc = BB / nc;
    float* fusedb = (float*)(ws + fixed_bytes);

    prep_kernel<<<618, 256, 0, stream>>>(gcb_w, Pm, gc1_w, P1, gc7_w, P7,
                                         mlp_w1, Pw1, mlp_w2, Pw2,
                                         gc1_att, gcb_att, gc7_att, attp, dctm, dtail);

    for (int ci = 0; ci < nc; ++ci) {
        const float* seqc = seq + (size_t)ci * Bc * TT * FF;
        float* outc = out + (size_t)ci * Bc * 480;
        gcn_fused_kernel<<<Bc, 256, 0, stream>>>(seqc, P1, Pm, P7, attp,
                                                 gc1_b, gcb_b, gc7_b, dctm, dtail, fusedb);
        ffc_mlp_kernel<<<Bc, 256, 0, stream>>>(seqc, fusedb, ffc_wl, ffc_wg, Pw1, Pw2, outc);
    }
}

// Round 10
// 284.852 us; speedup vs baseline: 1.1024x; 1.0776x over previous
//
#include <hip/hip_runtime.h>
#include <math.h>

#define BB 1024
#define TT 50
#define FF 48
#define EXTN 60
#define NFREQ 31

typedef _Float16 h8 __attribute__((ext_vector_type(8)));
typedef _Float16 h4 __attribute__((ext_vector_type(4)));
typedef float f4 __attribute__((ext_vector_type(4)));

__device__ __forceinline__ float fast_tanh(float x) {
    float e = __expf(2.0f * x);
    return 1.0f - 2.0f * __builtin_amdgcn_rcpf(e + 1.0f);
}

// =============== prep: pack ALL weights + DFT bases into MFMA-fragment order ===============
__global__ void prep_kernel(const float* __restrict__ gcb_w, _Float16* __restrict__ P,
                            const float* __restrict__ gc1_w, _Float16* __restrict__ P1,
                            const float* __restrict__ gc7_w, _Float16* __restrict__ P7,
                            const float* __restrict__ mlp_w1, _Float16* __restrict__ Pw1,
                            const float* __restrict__ mlp_w2, _Float16* __restrict__ Pw2,
                            const float* __restrict__ gc1_att, const float* __restrict__ gcb_att,
                            const float* __restrict__ gc7_att, _Float16* __restrict__ attp,
                            _Float16* __restrict__ Pc_hi, _Float16* __restrict__ Pc_lo,
                            _Float16* __restrict__ Pi_hi, _Float16* __restrict__ Pi_lo,
                            float* __restrict__ dctm, float* __restrict__ dtail) {
    int blk = blockIdx.x, tid = threadIdx.x;
    const _Float16 HZ = (_Float16)0.0f;
    if (blk < 512) {                    // big-layer weights, 4 x 512KB
        int z = blk >> 7;
        int idx = ((blk & 127) << 8) | tid;
        int lane = idx & 63, t8 = idx >> 6;
        int nt = t8 & 7, kw = t8 >> 3;
        int ks = kw & 15, wv = kw >> 4;
        int n = wv * 128 + nt * 16 + (lane & 15);
        int k0 = ks * 32 + (lane >> 4) * 8;
        const float* src = gcb_w + (size_t)z * 262144 + n;
        h8 v;
        #pragma unroll
        for (int j = 0; j < 8; ++j) v[j] = (_Float16)src[(size_t)(k0 + j) * 512];
        *(h8*)(P + (size_t)z * 262144 + (size_t)idx * 8) = v;
    } else if (blk < 528) {             // L1 weights (K=64 padded)
        int idx = ((blk - 512) << 8) | tid;
        int lane = idx & 63, t8 = idx >> 6;
        int nt = t8 & 7, kw = t8 >> 3;
        int ks = kw & 1, wv = kw >> 1;
        int n = wv * 128 + nt * 16 + (lane & 15);
        int k0 = ks * 32 + (lane >> 4) * 8;
        h8 v;
        #pragma unroll
        for (int j = 0; j < 8; ++j) v[j] = (k0 + j < 10) ? (_Float16)gc1_w[(k0 + j) * 512 + n] : HZ;
        *(h8*)(P1 + (size_t)idx * 8) = v;
    } else if (blk < 532) {             // L6 weights (N=16 padded, k split across waves)
        int idx = ((blk - 528) << 8) | tid;
        int lane = idx & 63, t8 = idx >> 6;
        int ks = t8 & 3, wv = t8 >> 2;
        int n = lane & 15;
        int k0 = wv * 128 + ks * 32 + (lane >> 4) * 8;
        h8 v;
        #pragma unroll
        for (int j = 0; j < 8; ++j) v[j] = (n < 10) ? (_Float16)gc7_w[(k0 + j) * 10 + n] : HZ;
        *(h8*)(P7 + (size_t)idx * 8) = v;
    } else if (blk < 540) {             // mlp w1 as B-frags (K=64 padded)
        int idx = ((blk - 532) << 8) | tid;
        int lane = idx & 63, t8 = idx >> 6;
        int ks = t8 & 1, q = t8 >> 1;
        int nt = q & 3, wv = q >> 2;
        int o = wv * 64 + nt * 16 + (lane & 15);
        int k0 = ks * 32 + (lane >> 4) * 8;
        h8 v;
        #pragma unroll
        for (int j = 0; j < 8; ++j) v[j] = (k0 + j < 40) ? (_Float16)mlp_w1[o * 40 + k0 + j] : HZ;
        *(h8*)(Pw1 + (size_t)idx * 8) = v;
    } else if (blk < 542) {             // mlp w2 as A-frags (M=16 padded rows t)
        int idx = ((blk - 540) << 8) | tid;
        int lane = idx & 63, ks = idx >> 6;
        int m = lane & 15;
        int k0 = ks * 32 + (lane >> 4) * 8;
        h8 v;
        #pragma unroll
        for (int j = 0; j < 8; ++j) v[j] = (m < 10) ? (_Float16)mlp_w2[m * 256 + k0 + j] : HZ;
        *(h8*)(Pw2 + (size_t)idx * 8) = v;
    } else if (blk < 614) {             // att matrices, k zero-padded to 64
        int idx = (blk - 542) * 256 + tid;
        if (idx < 18432) {
            int l = idx / 3072, r = (idx % 3072) / 64, m = idx & 63;
            float v = 0.f;
            if (m < 48) {
                v = (l == 0) ? gc1_att[r * 48 + m]
                  : (l <= 4) ? gcb_att[(l - 1) * 2304 + r * 48 + m]
                             : gc7_att[r * 48 + m];
            }
            attp[idx] = (_Float16)v;
        }
    } else if (blk < 646) {             // rfft basis B[t][n]: n<31 cos, 31..61 -sin; hi/lo split
        int g = (blk - 614) * 256 + tid;
        int tab = g >> 12, e = g & 4095;
        int j = e & 7, lane = (e >> 3) & 63, t8 = e >> 9;
        int ks = t8 & 1, nt = t8 >> 1;
        int n = nt * 16 + (lane & 15);
        int t = ks * 32 + (lane >> 4) * 8 + j;
        double v = 0.0;
        if (t < 60 && n < 62)
            v = (n < 31) ? cos(M_PI * (double)(n * t) / 30.0)
                         : -sin(M_PI * (double)((n - 31) * t) / 30.0);
        _Float16 hi = (_Float16)(float)v;
        if (tab == 0) Pc_hi[e] = hi;
        else          Pc_lo[e] = (_Float16)(float)(v - (double)(float)hi);
    } else if (blk < 654) {             // irfft basis B[k'][t] (coeffs folded); hi/lo split
        int g = (blk - 646) * 256 + tid;
        int tab = g >> 10, e = g & 1023;
        int j = e & 7, lane = (e >> 3) & 63, ks = e >> 9;
        int t = lane & 15;
        int kp = ks * 32 + (lane >> 4) * 8 + j;
        double v = 0.0;
        if (kp == 0) v = 1.0 / 60.0;
        else if (kp < 30) v = (2.0 / 60.0) * cos(M_PI * (double)(kp * t) / 30.0);
        else if (kp == 30) v = ((t & 1) ? -1.0 : 1.0) / 60.0;
        else if (kp >= 32 && kp < 61) v = -(2.0 / 60.0) * sin(M_PI * (double)((kp - 31) * t) / 30.0);
        _Float16 hi = (_Float16)(float)v;
        if (tab == 0) Pi_hi[e] = hi;
        else          Pi_lo[e] = (_Float16)(float)(v - (double)(float)hi);
    } else {                            // DCT tables
        int idx = (blk - 654) * 256 + tid;
        if (idx < 900) {
            int d = idx / 30, k = idx % 30;
            double w = (d == 0) ? sqrt(1.0 / 30.0) : sqrt(2.0 / 30.0);
            dctm[idx] = (float)(w * cos(M_PI * (k + 0.5) * d / 30.0));
        } else if (idx < 910) {
            int d = idx - 900;
            double w = (d == 0) ? sqrt(1.0 / 30.0) : sqrt(2.0 / 30.0);
            double s = 0.0;
            for (int k = 10; k < 30; ++k) s += w * cos(M_PI * (k + 0.5) * d / 30.0);
            dtail[d] = (float)s;
        }
    }
}

// =============== one GCN layer on LDS-resident state, packed weights ===============
// State S: 48 rows x 1024 B (512 f16), 16B granules XOR-swizzled by (row&7).
// K-loop single-buffered (register budget is saturated; prefetch spills — r8/r9).
// att frags loaded in the epilogue (B-frags dead there).
// MODE 0: tanh. MODE 1: tanh + save old state into sv. MODE 2: tanh + add sv.
template<int KSTEPS, int MODE>
__device__ __forceinline__ void gcn_layer(char* S, char* T,
        const _Float16* __restrict__ Pw, const _Float16* __restrict__ attp,
        const float* __restrict__ bias, h4* sv,
        int lane, int wv, int l16, int quad) {
    f4 acc[3][8];
    #pragma unroll
    for (int mt = 0; mt < 3; ++mt)
        #pragma unroll
        for (int nt = 0; nt < 8; ++nt) acc[mt][nt] = (f4)0.0f;

    const _Float16* Pb = Pw + (size_t)wv * (KSTEPS * 8 * 512) + lane * 8;
    const int xm = l16 & 7;
    __syncthreads();   // state ready

    #pragma unroll 2
    for (int ks = 0; ks < KSTEPS; ++ks) {
        h8 a[3], bfr[8];
        #pragma unroll
        for (int nt = 0; nt < 8; ++nt)
            bfr[nt] = *(const h8*)(Pb + (ks * 8 + nt) * 512);
        #pragma unroll
        for (int mt = 0; mt < 3; ++mt)
            a[mt] = *(h8*)(S + (mt * 16 + l16) * 1024 + (((ks * 4 + quad) ^ xm) << 4));
        #pragma unroll
        for (int mt = 0; mt < 3; ++mt)
            #pragma unroll
            for (int nt = 0; nt < 8; ++nt)
                acc[mt][nt] = __builtin_amdgcn_mfma_f32_16x16x32_f16(a[mt], bfr[nt], acc[mt][nt], 0, 0, 0);
    }
    __syncthreads();   // all reads done; epilogue may overwrite state

    h8 ab[3][2];
    #pragma unroll
    for (int it = 0; it < 3; ++it)
        #pragma unroll
        for (int ks = 0; ks < 2; ++ks)
            ab[it][ks] = *(const h8*)(attp + (it * 16 + l16) * 64 + ks * 32 + quad * 8);

    if (lane < 48) {
        int row = lane / 3, s = lane % 3;
        *(h8*)(T + row * 144 + 96 + s * 16) = (h8)(_Float16)0.0f;
    }

    #pragma unroll
    for (int nt = 0; nt < 8; ++nt) {
        #pragma unroll
        for (int mt = 0; mt < 3; ++mt) {
            h4 hv;
            #pragma unroll
            for (int j = 0; j < 4; ++j) hv[j] = (_Float16)acc[mt][nt][j];
            *(h4*)(T + l16 * 144 + (mt * 16 + quad * 4) * 2) = hv;
        }
        asm volatile("s_waitcnt lgkmcnt(0)" ::: "memory");
        h8 tf0 = *(h8*)(T + l16 * 144 + quad * 16);
        h8 tf1 = *(h8*)(T + l16 * 144 + 64 + quad * 16);
        f4 acc2[3];
        #pragma unroll
        for (int it = 0; it < 3; ++it) {
            acc2[it] = __builtin_amdgcn_mfma_f32_16x16x32_f16(tf0, ab[it][0], (f4)0.0f, 0, 0, 0);
            acc2[it] = __builtin_amdgcn_mfma_f32_16x16x32_f16(tf1, ab[it][1], acc2[it], 0, 0, 0);
        }
        const int c0 = wv * 128 + nt * 16 + quad * 4;
        const f4 bv = *(const f4*)(bias + c0);
        #pragma unroll
        for (int it = 0; it < 3; ++it) {
            int f = it * 16 + l16;
            char* sp = S + f * 1024 + (((c0 >> 3) ^ (f & 7)) << 4) + ((c0 & 7) << 1);
            if (MODE == 1) sv[nt * 3 + it] = *(h4*)sp;
            h4 o;
            #pragma unroll
            for (int j = 0; j < 4; ++j) {
                float v = fast_tanh(acc2[it][j] + bv[j]);
                if (MODE == 2) v += (float)sv[nt * 3 + it][j];
                o[j] = (_Float16)v;
            }
            *(h4*)sp = o;
        }
    }
}

// =============== fused GCN: dct_in + L1..L6 + recon, one WG per batch ===============
__launch_bounds__(256, 2)
__global__ void gcn_fused_kernel(const float* __restrict__ seq,
                                 const _Float16* __restrict__ P1,
                                 const _Float16* __restrict__ Pm,
                                 const _Float16* __restrict__ P7,
                                 const _Float16* __restrict__ attp,
                                 const float* __restrict__ gc1_b,
                                 const float* __restrict__ gcb_b,
                                 const float* __restrict__ gc7_b,
                                 const float* __restrict__ dctm,
                                 const float* __restrict__ dtail,
                                 float* __restrict__ fusedb) {
    __shared__ __align__(16) char smem[63744];
    char* S    = smem;              // 48 x 1024 state
    char* R    = smem + 49152;      // 12288: staging / transit / L6 partials / G
    char* dctf = smem + 61440;      // 48 x 12 f32 (dct_in, resid for L6)
    const int tid = threadIdx.x, lane = tid & 63, wv = tid >> 6;
    const int l16 = lane & 15, quad = lane >> 4;
    const int b = blockIdx.x;
    char* T = R + wv * 2304;

    // ---- prologue: seq rows 40..49 + DCT tables -> dct_in -> state ----
    if (tid < 120) *(f4*)(R + tid * 16) = *(const f4*)(seq + (size_t)b * 2400 + 1920 + tid * 4);
    for (int v = tid; v < 310; v += 256)
        ((float*)(R + 2048))[v] = (v < 300) ? dctm[v] : dtail[v - 300];
    __syncthreads();
    for (int v = tid; v < 480; v += 256) {
        int f = v / 10, d = v % 10;
        const float* q = (const float*)R;
        const float* L = (const float*)(R + 2048);
        float a = L[300 + d] * q[9 * 48 + f];
        #pragma unroll
        for (int k = 0; k < 10; ++k) a += L[d * 30 + k] * q[k * 48 + f];
        ((float*)dctf)[f * 12 + d] = a;
    }
    __syncthreads();
    for (int v = tid; v < 384; v += 256) {
        int m = v >> 3, g = v & 7;
        h8 w = (h8)(_Float16)0.0f;
        if (g < 2) {
            #pragma unroll
            for (int j = 0; j < 8; ++j) {
                int d = g * 8 + j;
                if (d < 10) w[j] = (_Float16)((float*)dctf)[m * 12 + d];
            }
        }
        *(h8*)(S + m * 1024 + ((g ^ (m & 7)) << 4)) = w;
    }

    h4 sv[24];
    gcn_layer<2, 0>(S, T, P1,          attp,          gc1_b,        sv, lane, wv, l16, quad);
    gcn_layer<16, 1>(S, T, Pm,          attp + 3072,  gcb_b,        sv, lane, wv, l16, quad);
    gcn_layer<16, 2>(S, T, Pm + 262144, attp + 6144,  gcb_b + 512,  sv, lane, wv, l16, quad);
    gcn_layer<16, 1>(S, T, Pm + 524288, attp + 9216,  gcb_b + 1024, sv, lane, wv, l16, quad);
    gcn_layer<16, 2>(S, T, Pm + 786432, attp + 12288, gcb_b + 1536, sv, lane, wv, l16, quad);

    // ---- L6 (gc7, N=16 padded) + recon ----
    __syncthreads();
    {
        f4 acc[3];
        #pragma unroll
        for (int mt = 0; mt < 3; ++mt) acc[mt] = (f4)0.0f;
        const _Float16* Pb7 = P7 + wv * 2048 + lane * 8;
        #pragma unroll
        for (int ks = 0; ks < 4; ++ks) {
            h8 bfr = *(const h8*)(Pb7 + ks * 512);
            int kh = wv * 128 + ks * 32;
            #pragma unroll
            for (int mt = 0; mt < 3; ++mt) {
                h8 a = *(h8*)(S + (mt * 16 + l16) * 1024 + ((((kh >> 3) + quad) ^ (l16 & 7)) << 4));
                acc[mt] = __builtin_amdgcn_mfma_f32_16x16x32_f16(a, bfr, acc[mt], 0, 0, 0);
            }
        }
        #pragma unroll
        for (int mt = 0; mt < 3; ++mt)
            *(f4*)(R + wv * 3072 + l16 * 192 + (mt * 16 + quad * 4) * 4) = acc[mt];
    }
    __syncthreads();
    if (wv == 0) {
        h4 tw[3]; int ns[3], ms[3];
        #pragma unroll
        for (int q = 0; q < 3; ++q) {
            int idx = lane * 3 + q;
            int n = idx / 12, m0 = (idx % 12) * 4;
            f4 s = *(f4*)(R + n * 192 + m0 * 4);
            s += *(f4*)(R + 3072 + n * 192 + m0 * 4);
            s += *(f4*)(R + 6144 + n * 192 + m0 * 4);
            s += *(f4*)(R + 9216 + n * 192 + m0 * 4);
            h4 h;
            #pragma unroll
            for (int j = 0; j < 4; ++j) h[j] = (_Float16)s[j];
            tw[q] = h; ns[q] = n; ms[q] = m0;
        }
        asm volatile("s_waitcnt lgkmcnt(0)" ::: "memory");
        #pragma unroll
        for (int q = 0; q < 3; ++q) *(h4*)(R + ns[q] * 144 + ms[q] * 2) = tw[q];
        if (lane < 48) {
            int row = lane / 3, s2 = lane % 3;
            *(h8*)(R + row * 144 + 96 + s2 * 16) = (h8)(_Float16)0.0f;
        }
        asm volatile("s_waitcnt lgkmcnt(0)" ::: "memory");
        h8 tf0 = *(h8*)(R + l16 * 144 + quad * 16);
        h8 tf1 = *(h8*)(R + l16 * 144 + 64 + quad * 16);
        const _Float16* a7 = attp + 15360;
        f4 acc2[3];
        #pragma unroll
        for (int it = 0; it < 3; ++it) {
            h8 ab0 = *(const h8*)(a7 + (it * 16 + l16) * 64 + quad * 8);
            h8 ab1 = *(const h8*)(a7 + (it * 16 + l16) * 64 + 32 + quad * 8);
            acc2[it] = __builtin_amdgcn_mfma_f32_16x16x32_f16(tf0, ab0, (f4)0.0f, 0, 0, 0);
            acc2[it] = __builtin_amdgcn_mfma_f32_16x16x32_f16(tf1, ab1, acc2[it], 0, 0, 0);
        }
        char* G = R + 4096;   // 48 x 16 f32
        #pragma unroll
        for (int it = 0; it < 3; ++it) {
            int f = it * 16 + l16;
            #pragma unroll
            for (int j = 0; j < 4; ++j) {
                int c = quad * 4 + j;
                if (c < 10) {
                    float v = acc2[it][j] + gc7_b[c] + ((float*)dctf)[f * 12 + c];
                    *(float*)(G + f * 64 + c * 4) = v;
                }
            }
        }
    }
    __syncthreads();
    {
        char* G = R + 4096;
        for (int v = tid; v < 1440; v += 256) {
            int f = v / 30, t = v % 30;
            float s = 0.f;
            #pragma unroll
            for (int d = 0; d < 10; ++d) s += dctm[d * 30 + t] * *(float*)(G + f * 64 + d * 4);
            fusedb[(size_t)b * 1440 + v] = s;
        }
    }
}

// =============== fused FFC (MFMA DFT, triple-f16) + MLP head (MFMA) ===============
__launch_bounds__(256, 2)
__global__ void ffc_mlp_kernel(const float* __restrict__ seq,
                               const float* __restrict__ fusedb,
                               const float* __restrict__ wl,
                               const float* __restrict__ wg,
                               const _Float16* __restrict__ Pw1,
                               const _Float16* __restrict__ Pw2,
                               const _Float16* __restrict__ Pc_hi,
                               const _Float16* __restrict__ Pc_lo,
                               const _Float16* __restrict__ Pi_hi,
                               const _Float16* __restrict__ Pi_lo,
                               float* __restrict__ out) {
    __shared__ __align__(16) char smem[58560];
    float* ext     = (float*)smem;               // [60][48] f32 (through irfft loc)
    char*  extT_hi = smem + 11520;               // 48 x 144B f16 (t-major, pad t>=60 = 0)
    char*  extT_lo = smem + 18432;               // -> 25344
    float* Xre     = (float*)(smem + 25344);     // [48][32]
    float* Xim     = (float*)(smem + 31488);     // -> 37632
    char*  Ya_hi   = smem + 37632;               // 48 x 144B (k'=0..30 re, 31..61 im)
    char*  Ya_lo   = smem + 44544;               // -> 51456
    _Float16* fus  = (_Float16*)(smem + 51456);  // [48][72] -> 58368
    float* wls     = (float*)(smem + 58368);     // 9
    float* wgs     = (float*)(smem + 58404);     // 36
    _Float16* hlds = (_Float16*)smem;            // [48][264] overlays ext+extT (mlp phase)
    char*  R2      = smem + 25344;               // 12288, overlays X (mlp2 partials)

    const int b = blockIdx.x, tid = threadIdx.x;
    const int lane = tid & 63, wv = tid >> 6;
    const int l16 = lane & 15, quad = lane >> 4;
    const float* s = seq + (size_t)b * TT * FF;

    // ---- stage ext (f32) and extT hi/lo (f16 split) ----
    for (int idx = tid; idx < EXTN * FF; idx += 256) {
        int t = idx / FF, f = idx % FF;
        ext[idx] = s[(t < TT ? t : TT - 1) * FF + f];
    }
    for (int idx = tid; idx < 64 * FF; idx += 256) {
        int t = idx / FF, f = idx % FF;
        float v = (t < EXTN) ? s[(t < TT ? t : TT - 1) * FF + f] : 0.f;
        _Float16 hi = (_Float16)v;
        ((_Float16*)(extT_hi + f * 144))[t] = hi;
        ((_Float16*)(extT_lo + f * 144))[t] = (_Float16)(v - (float)hi);
    }
    if (tid < 9) wls[tid] = wl[tid];
    if (tid >= 64 && tid < 100) wgs[tid - 64] = wg[tid - 64];
    __syncthreads();

    // ---- GEMM1: X = extT @ Crfft  (M=48, K=64, N=64; triple-f16) ----
    {
        const int nt = wv;
        f4 acc[3];
        #pragma unroll
        for (int mt = 0; mt < 3; ++mt) acc[mt] = (f4)0.0f;
        #pragma unroll
        for (int ks = 0; ks < 2; ++ks) {
            h8 bhi = *(const h8*)(Pc_hi + (nt * 2 + ks) * 512 + lane * 8);
            h8 blo = *(const h8*)(Pc_lo + (nt * 2 + ks) * 512 + lane * 8);
            #pragma unroll
            for (int mt = 0; mt < 3; ++mt) {
                h8 ahi = *(h8*)(extT_hi + (mt * 16 + l16) * 144 + ks * 64 + quad * 16);
                h8 alo = *(h8*)(extT_lo + (mt * 16 + l16) * 144 + ks * 64 + quad * 16);
                acc[mt] = __builtin_amdgcn_mfma_f32_16x16x32_f16(ahi, bhi, acc[mt], 0, 0, 0);
                acc[mt] = __builtin_amdgcn_mfma_f32_16x16x32_f16(alo, bhi, acc[mt], 0, 0, 0);
                acc[mt] = __builtin_amdgcn_mfma_f32_16x16x32_f16(ahi, blo, acc[mt], 0, 0, 0);
            }
        }
        int n = nt * 16 + l16;
        #pragma unroll
        for (int mt = 0; mt < 3; ++mt)
            #pragma unroll
            for (int i = 0; i < 4; ++i) {
                int f = mt * 16 + quad * 4 + i;
                if (n < 31) Xre[f * 32 + n] = acc[mt][i];
                else if (n < 62) Xim[f * 32 + n - 31] = acc[mt][i];
            }
    }
    __syncthreads();

    // ---- channel mix (6x6) + relu -> Ya hi/lo ----
    for (int idx = tid; idx < 2976; idx += 256) {
        int k = idx % 31; int g = (idx / 31) % 16; int o = idx / (31 * 16);
        float v = wgs[o * 6 + 0] * Xre[g * 32 + k]        + wgs[o * 6 + 1] * Xre[(16 + g) * 32 + k]
                + wgs[o * 6 + 2] * Xre[(32 + g) * 32 + k] + wgs[o * 6 + 3] * Xim[g * 32 + k]
                + wgs[o * 6 + 4] * Xim[(16 + g) * 32 + k] + wgs[o * 6 + 5] * Xim[(32 + g) * 32 + k];
        v = fmaxf(v, 0.f);
        int fr = (o < 3) ? o * 16 + g : (o - 3) * 16 + g;
        int kp = (o < 3) ? k : 31 + k;
        _Float16 hi = (_Float16)v;
        ((_Float16*)(Ya_hi + fr * 144))[kp] = hi;
        ((_Float16*)(Ya_lo + fr * 144))[kp] = (_Float16)(v - (float)hi);
    }
    if (tid < 96) {   // zero Ya cols 62,63
        int f = tid >> 1, c = 62 + (tid & 1);
        ((_Float16*)(Ya_hi + f * 144))[c] = (_Float16)0.0f;
        ((_Float16*)(Ya_lo + f * 144))[c] = (_Float16)0.0f;
    }
    __syncthreads();

    // ---- recon fill + zero pad (global latency overlaps GEMM2) ----
    for (int v = tid; v < 1440; v += 256) {
        int f = v / 30, t = v % 30;
        fus[f * 72 + t] = (_Float16)fusedb[(size_t)b * 1440 + v];
    }
    for (int v = tid; v < 1152; v += 256) {
        int f = v / 24, t = 40 + v % 24;
        fus[f * 72 + t] = (_Float16)0.0f;
    }
    // ---- GEMM2: out10 = Ya @ Pi  (M=48, K=64, N=16; triple-f16) + local 3x3 mix ----
    if (wv < 3) {
        const int mt = wv;
        f4 ac = (f4)0.0f;
        #pragma unroll
        for (int ks = 0; ks < 2; ++ks) {
            h8 bhi = *(const h8*)(Pi_hi + ks * 512 + lane * 8);
            h8 blo = *(const h8*)(Pi_lo + ks * 512 + lane * 8);
            h8 ahi = *(h8*)(Ya_hi + (mt * 16 + l16) * 144 + ks * 64 + quad * 16);
            h8 alo = *(h8*)(Ya_lo + (mt * 16 + l16) * 144 + ks * 64 + quad * 16);
            ac = __builtin_amdgcn_mfma_f32_16x16x32_f16(ahi, bhi, ac, 0, 0, 0);
            ac = __builtin_amdgcn_mfma_f32_16x16x32_f16(alo, bhi, ac, 0, 0, 0);
            ac = __builtin_amdgcn_mfma_f32_16x16x32_f16(ahi, blo, ac, 0, 0, 0);
        }
        int t = l16;
        if (t < 10) {
            #pragma unroll
            for (int i = 0; i < 4; ++i) {
                int g = quad * 4 + i;
                int f = mt * 16 + g;
                float loc = wls[mt * 3 + 0] * ext[t * FF + g]
                          + wls[mt * 3 + 1] * ext[t * FF + 16 + g]
                          + wls[mt * 3 + 2] * ext[t * FF + 32 + g];
                fus[f * 72 + 30 + t] = (_Float16)(ac[i] + loc);
            }
        }
    }
    __syncthreads();

    // ---- mlp1: h = relu(fus @ w1^T) via MFMA; per wave o-slice 64 ----
    f4 acc1[3][4];
    #pragma unroll
    for (int mt = 0; mt < 3; ++mt)
        #pragma unroll
        for (int nt = 0; nt < 4; ++nt) acc1[mt][nt] = (f4)0.0f;
    #pragma unroll
    for (int ks = 0; ks < 2; ++ks) {
        h8 af[3], bf[4];
        #pragma unroll
        for (int mt = 0; mt < 3; ++mt)
            af[mt] = *(h8*)((char*)fus + (mt * 16 + l16) * 144 + ks * 64 + quad * 16);
        #pragma unroll
        for (int nt = 0; nt < 4; ++nt)
            bf[nt] = *(const h8*)(Pw1 + (size_t)(((wv * 4 + nt) * 2 + ks) * 512) + lane * 8);
        #pragma unroll
        for (int mt = 0; mt < 3; ++mt)
            #pragma unroll
            for (int nt = 0; nt < 4; ++nt)
                acc1[mt][nt] = __builtin_amdgcn_mfma_f32_16x16x32_f16(af[mt], bf[nt], acc1[mt][nt], 0, 0, 0);
    }
    __syncthreads();   // ext/extT dead -> hlds region free
    #pragma unroll
    for (int mt = 0; mt < 3; ++mt)
        #pragma unroll
        for (int nt = 0; nt < 4; ++nt) {
            int o = wv * 64 + nt * 16 + l16;
            #pragma unroll
            for (int j = 0; j < 4; ++j) {
                int f = mt * 16 + quad * 4 + j;
                hlds[f * 264 + o] = (_Float16)fmaxf(acc1[mt][nt][j], 0.f);
            }
        }
    __syncthreads();
    // ---- mlp2: out^T[t][f] = w2 @ h^T via MFMA, k split across waves ----
    f4 acc2[3];
    #pragma unroll
    for (int nt3 = 0; nt3 < 3; ++nt3) acc2[nt3] = (f4)0.0f;
    #pragma unroll
    for (int ss = 0; ss < 2; ++ss) {
        int ks = wv * 2 + ss;
        h8 aw = *(const h8*)(Pw2 + (size_t)ks * 512 + lane * 8);
        #pragma unroll
        for (int nt3 = 0; nt3 < 3; ++nt3) {
            h8 bh = *(h8*)((char*)hlds + (nt3 * 16 + l16) * 528 + ks * 64 + quad * 16);
            acc2[nt3] = __builtin_amdgcn_mfma_f32_16x16x32_f16(aw, bh, acc2[nt3], 0, 0, 0);
        }
    }
    #pragma unroll
    for (int nt3 = 0; nt3 < 3; ++nt3)
        *(f4*)(R2 + wv * 3072 + (nt3 * 16 + l16) * 64 + quad * 16) = acc2[nt3];
    __syncthreads();
    for (int v = tid; v < 768; v += 256) {
        int f = v >> 4, t = v & 15;
        float sm = 0.f;
        #pragma unroll
        for (int w4 = 0; w4 < 4; ++w4) sm += *(float*)(R2 + w4 * 3072 + f * 64 + t * 4);
        if (t < 10) out[(size_t)b * 480 + t * 48 + f] = sm;
    }
}

extern "C" void kernel_launch(void* const* d_in, const int* in_sizes, int n_in,
                              void* d_out, int out_size, void* d_ws, size_t ws_size,
                              hipStream_t stream) {
    (void)in_sizes; (void)n_in; (void)out_size;
    const float* seq     = (const float*)d_in[0];
    // d_in[1..4] = wq1,wq2,wk1,wk2 — dead (attention branch sliced away by combined[:,:,:10])
    const float* gc1_w   = (const float*)d_in[5];
    const float* gc1_att = (const float*)d_in[6];
    const float* gc1_b   = (const float*)d_in[7];
    const float* gcb_w   = (const float*)d_in[8];
    const float* gcb_att = (const float*)d_in[9];
    const float* gcb_b   = (const float*)d_in[10];
    const float* gc7_w   = (const float*)d_in[11];
    const float* gc7_att = (const float*)d_in[12];
    const float* gc7_b   = (const float*)d_in[13];
    const float* mlp_w1  = (const float*)d_in[14];
    const float* mlp_w2  = (const float*)d_in[15];
    const float* ffc_wl  = (const float*)d_in[16];
    const float* ffc_wg  = (const float*)d_in[17];
    float* out = (float*)d_out;
    char* ws = (char*)d_ws;

    // fixed region (16B-aligned slabs)
    float*    dctm  = (float*)ws;                      // 900 f
    float*    dtail = dctm + 900;                      // 10 f
    char*     p0    = ws + 4096;
    _Float16* Pm    = (_Float16*)p0;   p0 += 4 * 262144 * 2;   // packed big-layer weights
    _Float16* P1    = (_Float16*)p0;   p0 += 32768 * 2;
    _Float16* P7    = (_Float16*)p0;   p0 += 8192 * 2;
    _Float16* Pw1   = (_Float16*)p0;   p0 += 16384 * 2;
    _Float16* Pw2   = (_Float16*)p0;   p0 += 4096 * 2;
    _Float16* attp  = (_Float16*)p0;   p0 += 18432 * 2;
    _Float16* Pc_hi = (_Float16*)p0;   p0 += 4096 * 2;
    _Float16* Pc_lo = (_Float16*)p0;   p0 += 4096 * 2;
    _Float16* Pi_hi = (_Float16*)p0;   p0 += 1024 * 2;
    _Float16* Pi_lo = (_Float16*)p0;   p0 += 1024 * 2;
    const size_t fixed_bytes = (size_t)(p0 - ws);

    const size_t per_batch = 5760;   // fusedb: 48 x 30 f32
    size_t avail = (ws_size > fixed_bytes) ? (ws_size - fixed_bytes) : 0;
    int nc = 1;
    while ((size_t)(BB / nc) * per_batch > avail && nc < 64) nc *= 2;
    int Bc = BB / nc;
    float* fusedb = (float*)(ws + fixed_bytes);

    prep_kernel<<<658, 256, 0, stream>>>(gcb_w, Pm, gc1_w, P1, gc7_w, P7,
                                         mlp_w1, Pw1, mlp_w2, Pw2,
                                         gc1_att, gcb_att, gc7_att, attp,
                                         Pc_hi, Pc_lo, Pi_hi, Pi_lo, dctm, dtail);

    for (int ci = 0; ci < nc; ++ci) {
        const float* seqc = seq + (size_t)ci * Bc * TT * FF;
        float* outc = out + (size_t)ci * Bc * 480;
        gcn_fused_kernel<<<Bc, 256, 0, stream>>>(seqc, P1, Pm, P7, attp,
                                                 gc1_b, gcb_b, gc7_b, dctm, dtail, fusedb);
        ffc_mlp_kernel<<<Bc, 256, 0, stream>>>(seqc, fusedb, ffc_wl, ffc_wg, Pw1, Pw2,
                                               Pc_hi, Pc_lo, Pi_hi, Pi_lo, outc);
    }
}

// Round 11
// 275.811 us; speedup vs baseline: 1.1385x; 1.0328x over previous
//
#include <hip/hip_runtime.h>
#include <math.h>

#define BB 1024
#define TT 50
#define FF 48
#define EXTN 60
#define NFREQ 31

typedef _Float16 h8 __attribute__((ext_vector_type(8)));
typedef _Float16 h4 __attribute__((ext_vector_type(4)));
typedef float f4 __attribute__((ext_vector_type(4)));

__device__ __forceinline__ float fast_tanh(float x) {
    float e = __expf(2.0f * x);
    return 1.0f - 2.0f * __builtin_amdgcn_rcpf(e + 1.0f);
}

// =============== prep: pack ALL weights + DFT bases into MFMA-fragment order ===============
__global__ void prep_kernel(const float* __restrict__ gcb_w, _Float16* __restrict__ P,
                            const float* __restrict__ gc1_w, _Float16* __restrict__ P1,
                            const float* __restrict__ gc7_w, _Float16* __restrict__ P7,
                            const float* __restrict__ mlp_w1, _Float16* __restrict__ Pw1,
                            const float* __restrict__ mlp_w2, _Float16* __restrict__ Pw2,
                            const float* __restrict__ gc1_att, const float* __restrict__ gcb_att,
                            const float* __restrict__ gc7_att, _Float16* __restrict__ attp,
                            _Float16* __restrict__ Pc_hi, _Float16* __restrict__ Pc_lo,
                            _Float16* __restrict__ Pi_hi, _Float16* __restrict__ Pi_lo,
                            float* __restrict__ dctm, float* __restrict__ dtail) {
    int blk = blockIdx.x, tid = threadIdx.x;
    const _Float16 HZ = (_Float16)0.0f;
    if (blk < 512) {                    // big-layer weights, 4 x 512KB
        int z = blk >> 7;
        int idx = ((blk & 127) << 8) | tid;
        int lane = idx & 63, t8 = idx >> 6;
        int nt = t8 & 7, kw = t8 >> 3;
        int ks = kw & 15, wv = kw >> 4;
        int n = wv * 128 + nt * 16 + (lane & 15);
        int k0 = ks * 32 + (lane >> 4) * 8;
        const float* src = gcb_w + (size_t)z * 262144 + n;
        h8 v;
        #pragma unroll
        for (int j = 0; j < 8; ++j) v[j] = (_Float16)src[(size_t)(k0 + j) * 512];
        *(h8*)(P + (size_t)z * 262144 + (size_t)idx * 8) = v;
    } else if (blk < 528) {             // L1 weights (K=64 padded)
        int idx = ((blk - 512) << 8) | tid;
        int lane = idx & 63, t8 = idx >> 6;
        int nt = t8 & 7, kw = t8 >> 3;
        int ks = kw & 1, wv = kw >> 1;
        int n = wv * 128 + nt * 16 + (lane & 15);
        int k0 = ks * 32 + (lane >> 4) * 8;
        h8 v;
        #pragma unroll
        for (int j = 0; j < 8; ++j) v[j] = (k0 + j < 10) ? (_Float16)gc1_w[(k0 + j) * 512 + n] : HZ;
        *(h8*)(P1 + (size_t)idx * 8) = v;
    } else if (blk < 532) {             // L6 weights (N=16 padded, k split across waves)
        int idx = ((blk - 528) << 8) | tid;
        int lane = idx & 63, t8 = idx >> 6;
        int ks = t8 & 3, wv = t8 >> 2;
        int n = lane & 15;
        int k0 = wv * 128 + ks * 32 + (lane >> 4) * 8;
        h8 v;
        #pragma unroll
        for (int j = 0; j < 8; ++j) v[j] = (n < 10) ? (_Float16)gc7_w[(k0 + j) * 10 + n] : HZ;
        *(h8*)(P7 + (size_t)idx * 8) = v;
    } else if (blk < 540) {             // mlp w1 as B-frags (K=64 padded)
        int idx = ((blk - 532) << 8) | tid;
        int lane = idx & 63, t8 = idx >> 6;
        int ks = t8 & 1, q = t8 >> 1;
        int nt = q & 3, wv = q >> 2;
        int o = wv * 64 + nt * 16 + (lane & 15);
        int k0 = ks * 32 + (lane >> 4) * 8;
        h8 v;
        #pragma unroll
        for (int j = 0; j < 8; ++j) v[j] = (k0 + j < 40) ? (_Float16)mlp_w1[o * 40 + k0 + j] : HZ;
        *(h8*)(Pw1 + (size_t)idx * 8) = v;
    } else if (blk < 542) {             // mlp w2 as A-frags (M=16 padded rows t)
        int idx = ((blk - 540) << 8) | tid;
        int lane = idx & 63, ks = idx >> 6;
        int m = lane & 15;
        int k0 = ks * 32 + (lane >> 4) * 8;
        h8 v;
        #pragma unroll
        for (int j = 0; j < 8; ++j) v[j] = (m < 10) ? (_Float16)mlp_w2[m * 256 + k0 + j] : HZ;
        *(h8*)(Pw2 + (size_t)idx * 8) = v;
    } else if (blk < 614) {             // att matrices, k zero-padded to 64
        int idx = (blk - 542) * 256 + tid;
        if (idx < 18432) {
            int l = idx / 3072, r = (idx % 3072) / 64, m = idx & 63;
            float v = 0.f;
            if (m < 48) {
                v = (l == 0) ? gc1_att[r * 48 + m]
                  : (l <= 4) ? gcb_att[(l - 1) * 2304 + r * 48 + m]
                             : gc7_att[r * 48 + m];
            }
            attp[idx] = (_Float16)v;
        }
    } else if (blk < 646) {             // rfft basis B[t][n]: n<31 cos, 31..61 -sin; hi/lo split
        int g = (blk - 614) * 256 + tid;
        int tab = g >> 12, e = g & 4095;
        int j = e & 7, lane = (e >> 3) & 63, t8 = e >> 9;
        int ks = t8 & 1, nt = t8 >> 1;
        int n = nt * 16 + (lane & 15);
        int t = ks * 32 + (lane >> 4) * 8 + j;
        double v = 0.0;
        if (t < 60 && n < 62)
            v = (n < 31) ? cos(M_PI * (double)(n * t) / 30.0)
                         : -sin(M_PI * (double)((n - 31) * t) / 30.0);
        _Float16 hi = (_Float16)(float)v;
        if (tab == 0) Pc_hi[e] = hi;
        else          Pc_lo[e] = (_Float16)(float)(v - (double)(float)hi);
    } else if (blk < 654) {             // irfft basis B[k'][t] (coeffs folded); hi/lo split
        int g = (blk - 646) * 256 + tid;
        int tab = g >> 10, e = g & 1023;
        int j = e & 7, lane = (e >> 3) & 63, ks = e >> 9;
        int t = lane & 15;
        int kp = ks * 32 + (lane >> 4) * 8 + j;
        double v = 0.0;
        if (kp == 0) v = 1.0 / 60.0;
        else if (kp < 30) v = (2.0 / 60.0) * cos(M_PI * (double)(kp * t) / 30.0);
        else if (kp == 30) v = ((t & 1) ? -1.0 : 1.0) / 60.0;
        else if (kp >= 32 && kp < 61) v = -(2.0 / 60.0) * sin(M_PI * (double)((kp - 31) * t) / 30.0);
        _Float16 hi = (_Float16)(float)v;
        if (tab == 0) Pi_hi[e] = hi;
        else          Pi_lo[e] = (_Float16)(float)(v - (double)(float)hi);
    } else {                            // DCT tables
        int idx = (blk - 654) * 256 + tid;
        if (idx < 900) {
            int d = idx / 30, k = idx % 30;
            double w = (d == 0) ? sqrt(1.0 / 30.0) : sqrt(2.0 / 30.0);
            dctm[idx] = (float)(w * cos(M_PI * (k + 0.5) * d / 30.0));
        } else if (idx < 910) {
            int d = idx - 900;
            double w = (d == 0) ? sqrt(1.0 / 30.0) : sqrt(2.0 / 30.0);
            double s = 0.0;
            for (int k = 10; k < 30; ++k) s += w * cos(M_PI * (k + 0.5) * d / 30.0);
            dtail[d] = (float)s;
        }
    }
}

// =============== one GCN layer on LDS-resident state, packed weights ===============
// State S: 48 rows x 1024 B (512 f16), 16B granules XOR-swizzled by (row&7).
// K-loop single-buffered (prefetch spills — r8/r9); att frags preloaded (r7: free at VGPR 128).
// MODE 0: tanh. MODE 1: tanh + save old state into sv. MODE 2: tanh + add sv.
template<int KSTEPS, int MODE>
__device__ __forceinline__ void gcn_layer(char* S, char* T,
        const _Float16* __restrict__ Pw, const _Float16* __restrict__ attp,
        const float* __restrict__ bias, h4* sv,
        int lane, int wv, int l16, int quad) {
    h8 ab[3][2];
    #pragma unroll
    for (int it = 0; it < 3; ++it)
        #pragma unroll
        for (int ks = 0; ks < 2; ++ks)
            ab[it][ks] = *(const h8*)(attp + (it * 16 + l16) * 64 + ks * 32 + quad * 8);

    f4 acc[3][8];
    #pragma unroll
    for (int mt = 0; mt < 3; ++mt)
        #pragma unroll
        for (int nt = 0; nt < 8; ++nt) acc[mt][nt] = (f4)0.0f;

    const _Float16* Pb = Pw + (size_t)wv * (KSTEPS * 8 * 512) + lane * 8;
    const int xm = l16 & 7;
    __syncthreads();   // state ready

    #pragma unroll 2
    for (int ks = 0; ks < KSTEPS; ++ks) {
        h8 a[3], bfr[8];
        #pragma unroll
        for (int nt = 0; nt < 8; ++nt)
            bfr[nt] = *(const h8*)(Pb + (ks * 8 + nt) * 512);
        #pragma unroll
        for (int mt = 0; mt < 3; ++mt)
            a[mt] = *(h8*)(S + (mt * 16 + l16) * 1024 + (((ks * 4 + quad) ^ xm) << 4));
        #pragma unroll
        for (int mt = 0; mt < 3; ++mt)
            #pragma unroll
            for (int nt = 0; nt < 8; ++nt)
                acc[mt][nt] = __builtin_amdgcn_mfma_f32_16x16x32_f16(a[mt], bfr[nt], acc[mt][nt], 0, 0, 0);
    }
    __syncthreads();   // all reads done; epilogue may overwrite state

    if (lane < 48) {
        int row = lane / 3, s = lane % 3;
        *(h8*)(T + row * 144 + 96 + s * 16) = (h8)(_Float16)0.0f;
    }

    #pragma unroll
    for (int nt = 0; nt < 8; ++nt) {
        #pragma unroll
        for (int mt = 0; mt < 3; ++mt) {
            h4 hv;
            #pragma unroll
            for (int j = 0; j < 4; ++j) hv[j] = (_Float16)acc[mt][nt][j];
            *(h4*)(T + l16 * 144 + (mt * 16 + quad * 4) * 2) = hv;
        }
        asm volatile("s_waitcnt lgkmcnt(0)" ::: "memory");
        h8 tf0 = *(h8*)(T + l16 * 144 + quad * 16);
        h8 tf1 = *(h8*)(T + l16 * 144 + 64 + quad * 16);
        f4 acc2[3];
        #pragma unroll
        for (int it = 0; it < 3; ++it) {
            acc2[it] = __builtin_amdgcn_mfma_f32_16x16x32_f16(tf0, ab[it][0], (f4)0.0f, 0, 0, 0);
            acc2[it] = __builtin_amdgcn_mfma_f32_16x16x32_f16(tf1, ab[it][1], acc2[it], 0, 0, 0);
        }
        const int c0 = wv * 128 + nt * 16 + quad * 4;
        const f4 bv = *(const f4*)(bias + c0);
        #pragma unroll
        for (int it = 0; it < 3; ++it) {
            int f = it * 16 + l16;
            char* sp = S + f * 1024 + (((c0 >> 3) ^ (f & 7)) << 4) + ((c0 & 7) << 1);
            if (MODE == 1) sv[nt * 3 + it] = *(h4*)sp;
            h4 o;
            #pragma unroll
            for (int j = 0; j < 4; ++j) {
                float v = fast_tanh(acc2[it][j] + bv[j]);
                if (MODE == 2) v += (float)sv[nt * 3 + it][j];
                o[j] = (_Float16)v;
            }
            *(h4*)sp = o;
        }
    }
}

// =============== fused GCN: dct_in + L1..L6 + recon (f16 fus layout), one WG per batch ===========
__launch_bounds__(256, 2)
__global__ void gcn_fused_kernel(const float* __restrict__ seq,
                                 const _Float16* __restrict__ P1,
                                 const _Float16* __restrict__ Pm,
                                 const _Float16* __restrict__ P7,
                                 const _Float16* __restrict__ attp,
                                 const float* __restrict__ gc1_b,
                                 const float* __restrict__ gcb_b,
                                 const float* __restrict__ gc7_b,
                                 const float* __restrict__ dctm,
                                 const float* __restrict__ dtail,
                                 _Float16* __restrict__ fush) {
    __shared__ __align__(16) char smem[63744];
    char* S    = smem;              // 48 x 1024 state
    char* R    = smem + 49152;      // 12288: staging / transit / L6 partials / G
    char* dctf = smem + 61440;      // 48 x 12 f32 (dct_in, resid for L6)
    const int tid = threadIdx.x, lane = tid & 63, wv = tid >> 6;
    const int l16 = lane & 15, quad = lane >> 4;
    const int b = blockIdx.x;
    char* T = R + wv * 2304;

    // ---- prologue: seq rows 40..49 + DCT tables -> dct_in -> state ----
    if (tid < 120) *(f4*)(R + tid * 16) = *(const f4*)(seq + (size_t)b * 2400 + 1920 + tid * 4);
    for (int v = tid; v < 310; v += 256)
        ((float*)(R + 2048))[v] = (v < 300) ? dctm[v] : dtail[v - 300];
    __syncthreads();
    for (int v = tid; v < 480; v += 256) {
        int f = v / 10, d = v % 10;
        const float* q = (const float*)R;
        const float* L = (const float*)(R + 2048);
        float a = L[300 + d] * q[9 * 48 + f];
        #pragma unroll
        for (int k = 0; k < 10; ++k) a += L[d * 30 + k] * q[k * 48 + f];
        ((float*)dctf)[f * 12 + d] = a;
    }
    __syncthreads();
    for (int v = tid; v < 384; v += 256) {
        int m = v >> 3, g = v & 7;
        h8 w = (h8)(_Float16)0.0f;
        if (g < 2) {
            #pragma unroll
            for (int j = 0; j < 8; ++j) {
                int d = g * 8 + j;
                if (d < 10) w[j] = (_Float16)((float*)dctf)[m * 12 + d];
            }
        }
        *(h8*)(S + m * 1024 + ((g ^ (m & 7)) << 4)) = w;
    }

    h4 sv[24];
    gcn_layer<2, 0>(S, T, P1,          attp,          gc1_b,        sv, lane, wv, l16, quad);
    gcn_layer<16, 1>(S, T, Pm,          attp + 3072,  gcb_b,        sv, lane, wv, l16, quad);
    gcn_layer<16, 2>(S, T, Pm + 262144, attp + 6144,  gcb_b + 512,  sv, lane, wv, l16, quad);
    gcn_layer<16, 1>(S, T, Pm + 524288, attp + 9216,  gcb_b + 1024, sv, lane, wv, l16, quad);
    gcn_layer<16, 2>(S, T, Pm + 786432, attp + 12288, gcb_b + 1536, sv, lane, wv, l16, quad);

    // ---- L6 (gc7, N=16 padded) + recon ----
    __syncthreads();
    {
        f4 acc[3];
        #pragma unroll
        for (int mt = 0; mt < 3; ++mt) acc[mt] = (f4)0.0f;
        const _Float16* Pb7 = P7 + wv * 2048 + lane * 8;
        #pragma unroll
        for (int ks = 0; ks < 4; ++ks) {
            h8 bfr = *(const h8*)(Pb7 + ks * 512);
            int kh = wv * 128 + ks * 32;
            #pragma unroll
            for (int mt = 0; mt < 3; ++mt) {
                h8 a = *(h8*)(S + (mt * 16 + l16) * 1024 + ((((kh >> 3) + quad) ^ (l16 & 7)) << 4));
                acc[mt] = __builtin_amdgcn_mfma_f32_16x16x32_f16(a, bfr, acc[mt], 0, 0, 0);
            }
        }
        #pragma unroll
        for (int mt = 0; mt < 3; ++mt)
            *(f4*)(R + wv * 3072 + l16 * 192 + (mt * 16 + quad * 4) * 4) = acc[mt];
    }
    __syncthreads();
    if (wv == 0) {
        h4 tw[3]; int ns[3], ms[3];
        #pragma unroll
        for (int q = 0; q < 3; ++q) {
            int idx = lane * 3 + q;
            int n = idx / 12, m0 = (idx % 12) * 4;
            f4 s = *(f4*)(R + n * 192 + m0 * 4);
            s += *(f4*)(R + 3072 + n * 192 + m0 * 4);
            s += *(f4*)(R + 6144 + n * 192 + m0 * 4);
            s += *(f4*)(R + 9216 + n * 192 + m0 * 4);
            h4 h;
            #pragma unroll
            for (int j = 0; j < 4; ++j) h[j] = (_Float16)s[j];
            tw[q] = h; ns[q] = n; ms[q] = m0;
        }
        asm volatile("s_waitcnt lgkmcnt(0)" ::: "memory");
        #pragma unroll
        for (int q = 0; q < 3; ++q) *(h4*)(R + ns[q] * 144 + ms[q] * 2) = tw[q];
        if (lane < 48) {
            int row = lane / 3, s2 = lane % 3;
            *(h8*)(R + row * 144 + 96 + s2 * 16) = (h8)(_Float16)0.0f;
        }
        asm volatile("s_waitcnt lgkmcnt(0)" ::: "memory");
        h8 tf0 = *(h8*)(R + l16 * 144 + quad * 16);
        h8 tf1 = *(h8*)(R + l16 * 144 + 64 + quad * 16);
        const _Float16* a7 = attp + 15360;
        f4 acc2[3];
        #pragma unroll
        for (int it = 0; it < 3; ++it) {
            h8 ab0 = *(const h8*)(a7 + (it * 16 + l16) * 64 + quad * 8);
            h8 ab1 = *(const h8*)(a7 + (it * 16 + l16) * 64 + 32 + quad * 8);
            acc2[it] = __builtin_amdgcn_mfma_f32_16x16x32_f16(tf0, ab0, (f4)0.0f, 0, 0, 0);
            acc2[it] = __builtin_amdgcn_mfma_f32_16x16x32_f16(tf1, ab1, acc2[it], 0, 0, 0);
        }
        char* G = R + 4096;   // 48 x 16 f32
        #pragma unroll
        for (int it = 0; it < 3; ++it) {
            int f = it * 16 + l16;
            #pragma unroll
            for (int j = 0; j < 4; ++j) {
                int c = quad * 4 + j;
                if (c < 10) {
                    float v = acc2[it][j] + gc7_b[c] + ((float*)dctf)[f * 12 + c];
                    *(float*)(G + f * 64 + c * 4) = v;
                }
            }
        }
    }
    __syncthreads();
    {
        char* G = R + 4096;
        _Float16* fb = fush + (size_t)b * 3456;
        for (int v = tid; v < 1440; v += 256) {
            int f = v / 30, t = v % 30;
            float s = 0.f;
            #pragma unroll
            for (int d = 0; d < 10; ++d) s += dctm[d * 30 + t] * *(float*)(G + f * 64 + d * 4);
            fb[f * 72 + t] = (_Float16)s;
        }
        for (int v = tid; v < 1152; v += 256) {   // zero t = 40..63 (mlp pad)
            int f = v / 24, t = 40 + v % 24;
            fb[f * 72 + t] = (_Float16)0.0f;
        }
    }
}

// =============== fused FFC (MFMA DFT, triple-f16) + MLP head (MFMA), 3 blocks/CU ===============
__launch_bounds__(256, 3)
__global__ void ffc_mlp_kernel(const float* __restrict__ seq,
                               const _Float16* __restrict__ fush,
                               const float* __restrict__ wl,
                               const float* __restrict__ wg,
                               const _Float16* __restrict__ Pw1,
                               const _Float16* __restrict__ Pw2,
                               const _Float16* __restrict__ Pc_hi,
                               const _Float16* __restrict__ Pc_lo,
                               const _Float16* __restrict__ Pi_hi,
                               const _Float16* __restrict__ Pi_lo,
                               float* __restrict__ out) {
    __shared__ __align__(16) char smem[44736];
    float* ext     = (float*)smem;               // [60][48] f32 (live through GEMM2 loc)
    char*  extT_hi = smem + 11520;               // 48 x 144B (t-major, pad t>=60 = 0)
    char*  extT_lo = smem + 18432;               // -> 25344
    char*  Ya_hi   = extT_hi;                    // overlays extT (dead after GEMM1)
    char*  Ya_lo   = extT_lo;
    float* Xre     = (float*)(smem + 25344);     // [48][32]
    float* Xim     = (float*)(smem + 31488);     // -> 37632
    _Float16* fus  = (_Float16*)(smem + 37632);  // [48][72] -> 44544
    float* wls     = (float*)(smem + 44544);     // 9
    float* wgs     = (float*)(smem + 44580);     // 36 -> 44724
    _Float16* hlds = (_Float16*)smem;            // [48][264] overlays ext+extT/Ya (mlp phase)
    char*  R2      = smem + 25344;               // 12288, overlays X (mlp2 partials)

    const int b = blockIdx.x, tid = threadIdx.x;
    const int lane = tid & 63, wv = tid >> 6;
    const int l16 = lane & 15, quad = lane >> 4;
    const float* s = seq + (size_t)b * TT * FF;

    // ---- stage ext (f32) and extT hi/lo (f16 split) ----
    for (int idx = tid; idx < EXTN * FF; idx += 256) {
        int t = idx / FF, f = idx % FF;
        ext[idx] = s[(t < TT ? t : TT - 1) * FF + f];
    }
    for (int idx = tid; idx < 64 * FF; idx += 256) {
        int t = idx / FF, f = idx % FF;
        float v = (t < EXTN) ? s[(t < TT ? t : TT - 1) * FF + f] : 0.f;
        _Float16 hi = (_Float16)v;
        ((_Float16*)(extT_hi + f * 144))[t] = hi;
        ((_Float16*)(extT_lo + f * 144))[t] = (_Float16)(v - (float)hi);
    }
    if (tid < 9) wls[tid] = wl[tid];
    if (tid >= 64 && tid < 100) wgs[tid - 64] = wg[tid - 64];
    __syncthreads();

    // ---- GEMM1: X = extT @ Crfft  (M=48, K=64, N=64; triple-f16) ----
    {
        const int nt = wv;
        f4 acc[3];
        #pragma unroll
        for (int mt = 0; mt < 3; ++mt) acc[mt] = (f4)0.0f;
        #pragma unroll
        for (int ks = 0; ks < 2; ++ks) {
            h8 bhi = *(const h8*)(Pc_hi + (nt * 2 + ks) * 512 + lane * 8);
            h8 blo = *(const h8*)(Pc_lo + (nt * 2 + ks) * 512 + lane * 8);
            #pragma unroll
            for (int mt = 0; mt < 3; ++mt) {
                h8 ahi = *(h8*)(extT_hi + (mt * 16 + l16) * 144 + ks * 64 + quad * 16);
                h8 alo = *(h8*)(extT_lo + (mt * 16 + l16) * 144 + ks * 64 + quad * 16);
                acc[mt] = __builtin_amdgcn_mfma_f32_16x16x32_f16(ahi, bhi, acc[mt], 0, 0, 0);
                acc[mt] = __builtin_amdgcn_mfma_f32_16x16x32_f16(alo, bhi, acc[mt], 0, 0, 0);
                acc[mt] = __builtin_amdgcn_mfma_f32_16x16x32_f16(ahi, blo, acc[mt], 0, 0, 0);
            }
        }
        int n = nt * 16 + l16;
        #pragma unroll
        for (int mt = 0; mt < 3; ++mt)
            #pragma unroll
            for (int i = 0; i < 4; ++i) {
                int f = mt * 16 + quad * 4 + i;
                if (n < 31) Xre[f * 32 + n] = acc[mt][i];
                else if (n < 62) Xim[f * 32 + n - 31] = acc[mt][i];
            }
    }
    // ---- recon + pad copy from fush (coalesced h8; overlaps GEMM1 latency) ----
    for (int v = tid; v < 384; v += 256) {
        int f = v >> 3, g = v & 7;
        *(h8*)((char*)fus + f * 144 + g * 16) =
            *(const h8*)(fush + (size_t)b * 3456 + f * 72 + g * 8);
    }
    __syncthreads();

    // ---- channel mix (6x6) + relu -> Ya hi/lo (overlays extT) ----
    for (int idx = tid; idx < 2976; idx += 256) {
        int k = idx % 31; int g = (idx / 31) % 16; int o = idx / (31 * 16);
        float v = wgs[o * 6 + 0] * Xre[g * 32 + k]        + wgs[o * 6 + 1] * Xre[(16 + g) * 32 + k]
                + wgs[o * 6 + 2] * Xre[(32 + g) * 32 + k] + wgs[o * 6 + 3] * Xim[g * 32 + k]
                + wgs[o * 6 + 4] * Xim[(16 + g) * 32 + k] + wgs[o * 6 + 5] * Xim[(32 + g) * 32 + k];
        v = fmaxf(v, 0.f);
        int fr = (o < 3) ? o * 16 + g : (o - 3) * 16 + g;
        int kp = (o < 3) ? k : 31 + k;
        _Float16 hi = (_Float16)v;
        ((_Float16*)(Ya_hi + fr * 144))[kp] = hi;
        ((_Float16*)(Ya_lo + fr * 144))[kp] = (_Float16)(v - (float)hi);
    }
    if (tid < 96) {   // zero Ya cols 62,63
        int f = tid >> 1, c = 62 + (tid & 1);
        ((_Float16*)(Ya_hi + f * 144))[c] = (_Float16)0.0f;
        ((_Float16*)(Ya_lo + f * 144))[c] = (_Float16)0.0f;
    }
    __syncthreads();

    // ---- GEMM2: out10 = Ya @ Pi  (M=48, K=64, N=16; triple-f16) + local 3x3 mix ----
    if (wv < 3) {
        const int mt = wv;
        f4 ac = (f4)0.0f;
        #pragma unroll
        for (int ks = 0; ks < 2; ++ks) {
            h8 bhi = *(const h8*)(Pi_hi + ks * 512 + lane * 8);
            h8 blo = *(const h8*)(Pi_lo + ks * 512 + lane * 8);
            h8 ahi = *(h8*)(Ya_hi + (mt * 16 + l16) * 144 + ks * 64 + quad * 16);
            h8 alo = *(h8*)(Ya_lo + (mt * 16 + l16) * 144 + ks * 64 + quad * 16);
            ac = __builtin_amdgcn_mfma_f32_16x16x32_f16(ahi, bhi, ac, 0, 0, 0);
            ac = __builtin_amdgcn_mfma_f32_16x16x32_f16(alo, bhi, ac, 0, 0, 0);
            ac = __builtin_amdgcn_mfma_f32_16x16x32_f16(ahi, blo, ac, 0, 0, 0);
        }
        int t = l16;
        if (t < 10) {
            #pragma unroll
            for (int i = 0; i < 4; ++i) {
                int g = quad * 4 + i;
                int f = mt * 16 + g;
                float loc = wls[mt * 3 + 0] * ext[t * FF + g]
                          + wls[mt * 3 + 1] * ext[t * FF + 16 + g]
                          + wls[mt * 3 + 2] * ext[t * FF + 32 + g];
                fus[f * 72 + 30 + t] = (_Float16)(ac[i] + loc);
            }
        }
    }
    __syncthreads();

    // ---- mlp1: h = relu(fus @ w1^T) via MFMA; per wave o-slice 64 ----
    f4 acc1[3][4];
    #pragma unroll
    for (int mt = 0; mt < 3; ++mt)
        #pragma unroll
        for (int nt = 0; nt < 4; ++nt) acc1[mt][nt] = (f4)0.0f;
    #pragma unroll
    for (int ks = 0; ks < 2; ++ks) {
        h8 af[3], bf[4];
        #pragma unroll
        for (int mt = 0; mt < 3; ++mt)
            af[mt] = *(h8*)((char*)fus + (mt * 16 + l16) * 144 + ks * 64 + quad * 16);
        #pragma unroll
        for (int nt = 0; nt < 4; ++nt)
            bf[nt] = *(const h8*)(Pw1 + (size_t)(((wv * 4 + nt) * 2 + ks) * 512) + lane * 8);
        #pragma unroll
        for (int mt = 0; mt < 3; ++mt)
            #pragma unroll
            for (int nt = 0; nt < 4; ++nt)
                acc1[mt][nt] = __builtin_amdgcn_mfma_f32_16x16x32_f16(af[mt], bf[nt], acc1[mt][nt], 0, 0, 0);
    }
    __syncthreads();   // ext/extT/Ya dead -> hlds region free
    #pragma unroll
    for (int mt = 0; mt < 3; ++mt)
        #pragma unroll
        for (int nt = 0; nt < 4; ++nt) {
            int o = wv * 64 + nt * 16 + l16;
            #pragma unroll
            for (int j = 0; j < 4; ++j) {
                int f = mt * 16 + quad * 4 + j;
                hlds[f * 264 + o] = (_Float16)fmaxf(acc1[mt][nt][j], 0.f);
            }
        }
    __syncthreads();
    // ---- mlp2: out^T[t][f] = w2 @ h^T via MFMA, k split across waves ----
    f4 acc2[3];
    #pragma unroll
    for (int nt3 = 0; nt3 < 3; ++nt3) acc2[nt3] = (f4)0.0f;
    #pragma unroll
    for (int ss = 0; ss < 2; ++ss) {
        int ks = wv * 2 + ss;
        h8 aw = *(const h8*)(Pw2 + (size_t)ks * 512 + lane * 8);
        #pragma unroll
        for (int nt3 = 0; nt3 < 3; ++nt3) {
            h8 bh = *(h8*)((char*)hlds + (nt3 * 16 + l16) * 528 + ks * 64 + quad * 16);
            acc2[nt3] = __builtin_amdgcn_mfma_f32_16x16x32_f16(aw, bh, acc2[nt3], 0, 0, 0);
        }
    }
    #pragma unroll
    for (int nt3 = 0; nt3 < 3; ++nt3)
        *(f4*)(R2 + wv * 3072 + (nt3 * 16 + l16) * 64 + quad * 16) = acc2[nt3];
    __syncthreads();
    for (int v = tid; v < 768; v += 256) {
        int f = v >> 4, t = v & 15;
        float sm = 0.f;
        #pragma unroll
        for (int w4 = 0; w4 < 4; ++w4) sm += *(float*)(R2 + w4 * 3072 + f * 64 + t * 4);
        if (t < 10) out[(size_t)b * 480 + t * 48 + f] = sm;
    }
}

extern "C" void kernel_launch(void* const* d_in, const int* in_sizes, int n_in,
                              void* d_out, int out_size, void* d_ws, size_t ws_size,
                              hipStream_t stream) {
    (void)in_sizes; (void)n_in; (void)out_size;
    const float* seq     = (const float*)d_in[0];
    // d_in[1..4] = wq1,wq2,wk1,wk2 — dead (attention branch sliced away by combined[:,:,:10])
    const float* gc1_w   = (const float*)d_in[5];
    const float* gc1_att = (const float*)d_in[6];
    const float* gc1_b   = (const float*)d_in[7];
    const float* gcb_w   = (const float*)d_in[8];
    const float* gcb_att = (const float*)d_in[9];
    const float* gcb_b   = (const float*)d_in[10];
    const float* gc7_w   = (const float*)d_in[11];
    const float* gc7_att = (const float*)d_in[12];
    const float* gc7_b   = (const float*)d_in[13];
    const float* mlp_w1  = (const float*)d_in[14];
    const float* mlp_w2  = (const float*)d_in[15];
    const float* ffc_wl  = (const float*)d_in[16];
    const float* ffc_wg  = (const float*)d_in[17];
    float* out = (float*)d_out;
    char* ws = (char*)d_ws;

    // fixed region (16B-aligned slabs)
    float*    dctm  = (float*)ws;                      // 900 f
    float*    dtail = dctm + 900;                      // 10 f
    char*     p0    = ws + 4096;
    _Float16* Pm    = (_Float16*)p0;   p0 += 4 * 262144 * 2;   // packed big-layer weights
    _Float16* P1    = (_Float16*)p0;   p0 += 32768 * 2;
    _Float16* P7    = (_Float16*)p0;   p0 += 8192 * 2;
    _Float16* Pw1   = (_Float16*)p0;   p0 += 16384 * 2;
    _Float16* Pw2   = (_Float16*)p0;   p0 += 4096 * 2;
    _Float16* attp  = (_Float16*)p0;   p0 += 18432 * 2;
    _Float16* Pc_hi = (_Float16*)p0;   p0 += 4096 * 2;
    _Float16* Pc_lo = (_Float16*)p0;   p0 += 4096 * 2;
    _Float16* Pi_hi = (_Float16*)p0;   p0 += 1024 * 2;
    _Float16* Pi_lo = (_Float16*)p0;   p0 += 1024 * 2;
    const size_t fixed_bytes = (size_t)(p0 - ws);

    const size_t per_batch = 6912;   // fush: 48 x 72 f16
    size_t avail = (ws_size > fixed_bytes) ? (ws_size - fixed_bytes) : 0;
    int nc = 1;
    while ((size_t)(BB / nc) * per_batch > avail && nc < 64) nc *= 2;
    int Bc = BB / nc;
    _Float16* fush = (_Float16*)(ws + fixed_bytes);

    prep_kernel<<<658, 256, 0, stream>>>(gcb_w, Pm, gc1_w, P1, gc7_w, P7,
                                         mlp_w1, Pw1, mlp_w2, Pw2,
                                         gc1_att, gcb_att, gc7_att, attp,
                                         Pc_hi, Pc_lo, Pi_hi, Pi_lo, dctm, dtail);

    for (int ci = 0; ci < nc; ++ci) {
        const float* seqc = seq + (size_t)ci * Bc * TT * FF;
        float* outc = out + (size_t)ci * Bc * 480;
        gcn_fused_kernel<<<Bc, 256, 0, stream>>>(seqc, P1, Pm, P7, attp,
                                                 gc1_b, gcb_b, gc7_b, dctm, dtail, fush);
        ffc_mlp_kernel<<<Bc, 256, 0, stream>>>(seqc, fush, ffc_wl, ffc_wg, Pw1, Pw2,
                                               Pc_hi, Pc_lo, Pi_hi, Pi_lo, outc);
    }
}